// Round 2
// baseline (386.409 us; speedup 1.0000x reference)
//
#include <hip/hip_runtime.h>
#include <cmath>

typedef __bf16 bf16_t;
typedef bf16_t bf16x8 __attribute__((ext_vector_type(8)));
typedef bf16_t bf16x4 __attribute__((ext_vector_type(4)));
typedef float f32x4 __attribute__((ext_vector_type(4)));

#define DEVI static __device__ __forceinline__

constexpr int TB = 8;        // batch
constexpr int TT = 2048;     // seq len
constexpr int BT_ = TB * TT; // tokens
constexpr float EPS_LN = 1e-5f;

DEVI f32x4 mfma16(bf16x8 a, bf16x8 b, f32x4 c) {
  return __builtin_amdgcn_mfma_f32_16x16x32_bf16(a, b, c, 0, 0, 0);
}

DEVI bf16x8 cvt8(float4 a, float4 b) {
  bf16x8 v;
  v[0] = (bf16_t)a.x; v[1] = (bf16_t)a.y; v[2] = (bf16_t)a.z; v[3] = (bf16_t)a.w;
  v[4] = (bf16_t)b.x; v[5] = (bf16_t)b.y; v[6] = (bf16_t)b.z; v[7] = (bf16_t)b.w;
  return v;
}

DEVI void gload_lds16(const void* g, void* l) {
  __builtin_amdgcn_global_load_lds(
      (const __attribute__((address_space(1))) unsigned int*)g,
      (__attribute__((address_space(3))) unsigned int*)l, 16, 0, 0);
}

// ---------------------------------------------------------------------------
// K0: pre-pack all MFMA weights f32 -> bf16 in fragment-major layout:
//   frag[(n0*KS + ks)*64 + lane][j] = W[n0*16 + (lane&15)][ks*32 + (lane>>4)*8 + j]
// so a wave's B-fragment load is one fully-coalesced 1 KiB read from L2.
// Order in wf: Wq(16384) Wk(16384) Wv(16384) pc(32768) pu(32768) pd(32768)
// ---------------------------------------------------------------------------
__global__ __launch_bounds__(256) void k_prep(
    const float* __restrict__ Wq, const float* __restrict__ Wk,
    const float* __restrict__ Wv, const float* __restrict__ Wpc,
    const float* __restrict__ Wpu, const float* __restrict__ Wpd,
    bf16_t* __restrict__ wf) {
  int g = blockIdx.x * 256 + threadIdx.x;   // 18432 fragment-groups total
  const float* W;
  bf16_t* dst;
  int rel, lks, Kdim;
  if (g < 6144) {                 // Wq/Wk/Wv: 128x128, KS=4
    int m = g >> 11; rel = g & 2047;
    W = (m == 0) ? Wq : ((m == 1) ? Wk : Wv);
    dst = wf + m * 16384; lks = 2; Kdim = 128;
  } else if (g < 10240) {         // pc_w: 128x256, KS=8
    rel = g - 6144; W = Wpc; dst = wf + 49152; lks = 3; Kdim = 256;
  } else if (g < 14336) {         // pu_w: 256x128, KS=4
    rel = g - 10240; W = Wpu; dst = wf + 81920; lks = 2; Kdim = 128;
  } else {                        // pd_w: 128x256, KS=8
    rel = g - 14336; W = Wpd; dst = wf + 114688; lks = 3; Kdim = 256;
  }
  int lane = rel & 63;
  int fk = (rel >> 6) & ((1 << lks) - 1);
  int n0 = rel >> (6 + lks);
  int row = n0 * 16 + (lane & 15);
  int col = fk * 32 + (lane >> 4) * 8;
  const float* s = W + row * Kdim + col;
  float4 a = *(const float4*)s;
  float4 b = *(const float4*)(s + 4);
  *(bf16x8*)(dst + (size_t)rel * 8) = cvt8(a, b);
}

// ---------------------------------------------------------------------------
// K1: LN(cn) + Q/K/V projections (gate on Q,K). 64 tokens/block, 4 waves.
// Q,K stored [token][128] bf16; V stored transposed [b][dv=128][t=2048] bf16.
// ---------------------------------------------------------------------------
__global__ __launch_bounds__(256) void k_qkv(
    const float* __restrict__ x, const float* __restrict__ gate,
    const float* __restrict__ cn_g, const float* __restrict__ cn_b,
    const bf16_t* __restrict__ wf,
    bf16_t* __restrict__ Qo, bf16_t* __restrict__ Ko, bf16_t* __restrict__ Vt) {
  __shared__ __align__(16) bf16_t sH[64 * 128];   // swizzled 16B blocks
  const int tid = threadIdx.x;
  const int t0 = blockIdx.x * 64;

  { // LayerNorm: 4 threads per token, 32 elems each
    const int tok = tid >> 2, part = tid & 3;
    const float* xr = x + (size_t)(t0 + tok) * 128 + part * 32;
    float v[32];
    float s0 = 0.f, s1 = 0.f;
#pragma unroll
    for (int i = 0; i < 8; ++i) {
      float4 f = ((const float4*)xr)[i];
      v[i * 4 + 0] = f.x; v[i * 4 + 1] = f.y; v[i * 4 + 2] = f.z; v[i * 4 + 3] = f.w;
      s0 += f.x + f.y + f.z + f.w;
      s1 += f.x * f.x + f.y * f.y + f.z * f.z + f.w * f.w;
    }
    s0 += __shfl_xor(s0, 1); s0 += __shfl_xor(s0, 2);
    s1 += __shfl_xor(s1, 1); s1 += __shfl_xor(s1, 2);
    float mean = s0 * (1.f / 128.f);
    float var = s1 * (1.f / 128.f) - mean * mean;
    float rstd = rsqrtf(var + EPS_LN);
#pragma unroll
    for (int j8 = 0; j8 < 4; ++j8) {
      bf16x8 hv;
#pragma unroll
      for (int k = 0; k < 8; ++k) {
        int d = part * 32 + j8 * 8 + k;
        float hn = (v[j8 * 8 + k] - mean) * rstd;
        hv[k] = (bf16_t)(hn * cn_g[d] + cn_b[d]);
      }
      int bl = part * 4 + j8;
      *(bf16x8*)(&sH[tok * 128 + ((bl ^ (tok & 7)) * 8)]) = hv;
    }
  }
  __syncthreads();

  const int wave = tid >> 6, lane = tid & 63;
  const int rt = lane & 15, kg = lane >> 4;
  const int arow = wave * 16 + rt;
  bf16x8 af[4];
#pragma unroll
  for (int ks = 0; ks < 4; ++ks)
    af[ks] = *(const bf16x8*)(&sH[arow * 128 + (((ks * 4 + kg) ^ (rt & 7)) * 8)]);

  const int trow0 = t0 + wave * 16 + kg * 4;  // first of 4 output token rows
  float4 g4 = *(const float4*)(gate + trow0);
  float gr[4] = {g4.x, g4.y, g4.z, g4.w};
  const int b_ = trow0 >> 11;
  const int tloc = trow0 & 2047;

#pragma unroll
  for (int m = 0; m < 3; ++m) {
    const bf16_t* wm = wf + m * 16384;
#pragma unroll
    for (int n0 = 0; n0 < 8; ++n0) {
      f32x4 acc = {0.f, 0.f, 0.f, 0.f};
#pragma unroll
      for (int ks = 0; ks < 4; ++ks) {
        bf16x8 bf = *(const bf16x8*)(wm + ((size_t)(n0 * 4 + ks) * 64 + lane) * 8);
        acc = mfma16(af[ks], bf, acc);
      }
      if (m == 2) {
        bf16x4 pk;
        pk[0] = (bf16_t)acc[0]; pk[1] = (bf16_t)acc[1];
        pk[2] = (bf16_t)acc[2]; pk[3] = (bf16_t)acc[3];
        *(bf16x4*)(Vt + ((size_t)(b_ * 128 + n0 * 16 + rt)) * 2048 + tloc) = pk;
      } else {
        bf16_t* O = (m == 0) ? Qo : Ko;
#pragma unroll
        for (int r = 0; r < 4; ++r)
          O[(size_t)(trow0 + r) * 128 + n0 * 16 + rt] = (bf16_t)(acc[r] * gr[r]);
      }
    }
  }
}

// ---------------------------------------------------------------------------
// K2: boundary v_scores (all fp32 vector math) + per-block |.| partial sums.
// 64 tokens/block, 4 lanes/token.
// ---------------------------------------------------------------------------
__global__ __launch_bounds__(256) void k_vscores(
    const float* __restrict__ x, const float* __restrict__ bn_g,
    const float* __restrict__ bn_b, const float* __restrict__ Wg_w,
    const float* __restrict__ Wg_b, const float* __restrict__ nb6,
    const float* __restrict__ g2v, const float* __restrict__ vemb,
    const float* __restrict__ adj, const float* __restrict__ spec,
    const float* __restrict__ wspec,
    float* __restrict__ vs_out, float* __restrict__ psum) {
  __shared__ float sWg[768];
  __shared__ float sG2V[192];
  __shared__ float sVE[64 * 33];
  __shared__ float sSP[64 * 33];
  __shared__ float sADJ[64 * 64];
  __shared__ float sRaw[64 * 68];
  __shared__ float sBN[256];
  __shared__ float bsum;
  const int tid = threadIdx.x;
  const int t0 = blockIdx.x * 64;
  if (tid == 0) bsum = 0.f;
  for (int i = tid; i < 768; i += 256) sWg[i] = Wg_w[i];
  for (int i = tid; i < 192; i += 256) sG2V[i] = g2v[i];
  for (int i = tid; i < 256; i += 256) sBN[i] = (i < 128) ? bn_g[i] : bn_b[i - 128];
  for (int i = tid; i < 2048; i += 256) sVE[(i >> 5) * 33 + (i & 31)] = vemb[i];
  for (int i = tid; i < 4096; i += 256) sADJ[i] = adj[i];
  for (int i = tid; i < 2048; i += 256) {
    int s = i >> 5, vv = i & 31;
    float acc = 0.f;
#pragma unroll
    for (int e = 0; e < 16; ++e) acc += spec[s * 16 + e] * wspec[vv * 16 + e];
    sSP[s * 33 + vv] = acc;
  }
  __syncthreads();

  const int tok = tid >> 2, part = tid & 3;
  const float* xr = x + (size_t)(t0 + tok) * 128 + part * 32;
  float v[32];
  float s0 = 0.f, s1 = 0.f;
#pragma unroll
  for (int i = 0; i < 8; ++i) {
    float4 f = ((const float4*)xr)[i];
    v[i * 4 + 0] = f.x; v[i * 4 + 1] = f.y; v[i * 4 + 2] = f.z; v[i * 4 + 3] = f.w;
    s0 += f.x + f.y + f.z + f.w;
    s1 += f.x * f.x + f.y * f.y + f.z * f.z + f.w * f.w;
  }
  s0 += __shfl_xor(s0, 1); s0 += __shfl_xor(s0, 2);
  s1 += __shfl_xor(s1, 1); s1 += __shfl_xor(s1, 2);
  float mean = s0 * (1.f / 128.f);
  float rstd = rsqrtf(s1 * (1.f / 128.f) - mean * mean + EPS_LN);
  float hb[32];
#pragma unroll
  for (int k = 0; k < 32; ++k) {
    int d = part * 32 + k;
    hb[k] = (v[k] - mean) * rstd * sBN[d] + sBN[128 + d];
  }
  float g6[6];
#pragma unroll
  for (int j = 0; j < 6; ++j) {
    float a = 0.f;
#pragma unroll
    for (int k = 0; k < 32; ++k) a += hb[k] * sWg[j * 128 + part * 32 + k];
    a += __shfl_xor(a, 1); a += __shfl_xor(a, 2);
    a += Wg_b[j] + nb6[j];
    g6[j] = 1.f / (1.f + expf(-a));
  }
  float gp[32];
#pragma unroll
  for (int vv = 0; vv < 32; ++vv) {
    float a = 0.f;
#pragma unroll
    for (int j = 0; j < 6; ++j) a += g6[j] * sG2V[vv * 6 + j];
    gp[vv] = a;
  }
#pragma unroll
  for (int j = 0; j < 16; ++j) {
    int s = part * 16 + j;
    float a = 0.f;
#pragma unroll
    for (int vv = 0; vv < 32; ++vv)
      a += gp[vv] * (sVE[s * 33 + vv] + 0.1f * sSP[s * 33 + vv]);
    sRaw[tok * 68 + s] = a;
  }
  __syncthreads();

  float fin[16];
#pragma unroll
  for (int j = 0; j < 16; ++j) fin[j] = 0.f;
  for (int s = 0; s < 64; ++s) {
    float rv = sRaw[tok * 68 + s];
#pragma unroll
    for (int j = 0; j < 16; ++j) fin[j] += rv * sADJ[s * 64 + part * 16 + j];
  }
  float sa = 0.f;
#pragma unroll
  for (int j = 0; j < 16; ++j) {
    fin[j] = sRaw[tok * 68 + part * 16 + j] + 0.1f * fin[j];
    sa += fabsf(fin[j]);
  }
  float* o = vs_out + (size_t)(t0 + tok) * 64 + part * 16;
#pragma unroll
  for (int j4 = 0; j4 < 4; ++j4) {
    float4 f;
    f.x = fin[j4 * 4 + 0]; f.y = fin[j4 * 4 + 1];
    f.z = fin[j4 * 4 + 2]; f.w = fin[j4 * 4 + 3];
    ((float4*)o)[j4] = f;
  }
#pragma unroll
  for (int m = 1; m <= 32; m <<= 1) sa += __shfl_xor(sa, m);
  if ((tid & 63) == 0) atomicAdd(&bsum, sa);
  __syncthreads();
  if (tid == 0) psum[blockIdx.x] = bsum;
}

// ---------------------------------------------------------------------------
// K3: flash attention + alignment (pre-softmax scores) output + center signal.
// 64 q-rows/block, 4 waves x 16 rows. K tile and V^T tile staged with
// global_load_lds (16B), XOR-swizzled via pre-swizzled global source.
// XCD swizzle: b = blockIdx&7 so each XCD keeps one batch's K/V in its L2.
// ---------------------------------------------------------------------------
__global__ __launch_bounds__(256) void k_attn(
    const bf16_t* __restrict__ Q, const bf16_t* __restrict__ Kp,
    const bf16_t* __restrict__ Vt, const float* __restrict__ x,
    const float* __restrict__ mask,
    float* __restrict__ align_out, bf16_t* __restrict__ center) {
  __shared__ __align__(16) bf16_t sK[64 * 128];
  __shared__ __align__(16) bf16_t sV[128 * 64];
  __shared__ __align__(16) bf16_t sP[4][16 * 72];   // +8 pad per row
  const int tid = threadIdx.x;
  const int b_ = blockIdx.x & 7;
  const int qt = blockIdx.x >> 3;
  const int wave = tid >> 6, lane = tid & 63;
  const int rt = lane & 15, kg = lane >> 4;
  const size_t tq0 = (size_t)b_ * TT + qt * 64;

  bf16x8 qf[4];
#pragma unroll
  for (int ks = 0; ks < 4; ++ks)
    qf[ks] = *(const bf16x8*)(Q + (tq0 + wave * 16 + rt) * 128 + ks * 32 + kg * 8);

  f32x4 o[8];
  f32x4 zero4 = {0.f, 0.f, 0.f, 0.f};
#pragma unroll
  for (int i = 0; i < 8; ++i) o[i] = zero4;
  float m[4], l[4];
#pragma unroll
  for (int r = 0; r < 4; ++r) { m[r] = -INFINITY; l[r] = 0.f; }
  const float inv_sc = 0.08838834764831845f;  // 1/sqrt(128)
  const int tqr = qt * 64 + wave * 16 + kg * 4;
  const int koff = wave * 1024 + lane * 16;

  for (int st = 0; st < 32; ++st) {
    const int sb = st * 64;
    __syncthreads();   // previous tile fully consumed
    // stage K tile [64][128] bf16, swizzled source
#pragma unroll
    for (int i = 0; i < 4; ++i) {
      int off = i * 4096 + koff;
      int row = off >> 8;
      int c16 = (off >> 4) & 15;
      const char* src = (const char*)Kp +
          ((size_t)(b_ * TT + sb + row) * 128 + ((c16 ^ (row & 7)) * 8)) * 2;
      gload_lds16(src, (char*)sK + i * 4096 + wave * 1024);
    }
    // stage V^T tile [128][64] bf16
#pragma unroll
    for (int i = 0; i < 4; ++i) {
      int off = i * 4096 + koff;
      int row = off >> 7;
      int c16 = (off >> 4) & 7;
      const char* src = (const char*)Vt +
          ((size_t)(b_ * 128 + row) * 2048 + sb + ((c16 ^ (row & 7)) * 8)) * 2;
      gload_lds16(src, (char*)sV + i * 4096 + wave * 1024);
    }
    __syncthreads();   // drains vmcnt (incl. global_load_lds) then barrier

    // scores S = Q K^T / sqrt(D) + mask ; write alignment; online softmax
    float p[4][4];
#pragma unroll
    for (int ct = 0; ct < 4; ++ct) {
      const int brow = ct * 16 + rt;
      f32x4 acc = zero4;
#pragma unroll
      for (int ks = 0; ks < 4; ++ks) {
        bf16x8 kf = *(const bf16x8*)(&sK[brow * 128 + (((ks * 4 + kg) ^ (rt & 7)) * 8)]);
        acc = mfma16(qf[ks], kf, acc);
      }
      const int scol = sb + ct * 16 + rt;
#pragma unroll
      for (int r = 0; r < 4; ++r) {
        float sv = acc[r] * inv_sc + mask[(size_t)(tqr + r) * TT + scol];
        align_out[((size_t)b_ * TT + tqr + r) * TT + scol] = sv;
        p[ct][r] = sv;
      }
    }
    float mn[4], fsc[4];
#pragma unroll
    for (int r = 0; r < 4; ++r) {
      float pm = fmaxf(fmaxf(p[0][r], p[1][r]), fmaxf(p[2][r], p[3][r]));
#pragma unroll
      for (int dm = 1; dm <= 8; dm <<= 1) pm = fmaxf(pm, __shfl_xor(pm, dm));
      mn[r] = fmaxf(m[r], pm);
      fsc[r] = __expf(m[r] - mn[r]);
      m[r] = mn[r];
    }
    float rs[4] = {0.f, 0.f, 0.f, 0.f};
#pragma unroll
    for (int ct = 0; ct < 4; ++ct)
#pragma unroll
      for (int r = 0; r < 4; ++r) {
        float pe = __expf(p[ct][r] - mn[r]);
        p[ct][r] = pe;
        rs[r] += pe;
      }
#pragma unroll
    for (int r = 0; r < 4; ++r) {
#pragma unroll
      for (int dm = 1; dm <= 8; dm <<= 1) rs[r] += __shfl_xor(rs[r], dm);
      l[r] = l[r] * fsc[r] + rs[r];
    }
#pragma unroll
    for (int i = 0; i < 8; ++i) {
      o[i][0] *= fsc[0]; o[i][1] *= fsc[1]; o[i][2] *= fsc[2]; o[i][3] *= fsc[3];
    }
    // P -> bf16 -> per-wave LDS (padded rows; same-wave write->read, in-order DS)
#pragma unroll
    for (int ct = 0; ct < 4; ++ct)
#pragma unroll
      for (int r = 0; r < 4; ++r)
        sP[wave][(kg * 4 + r) * 72 + ct * 16 + rt] = (bf16_t)p[ct][r];
    asm volatile("" ::: "memory");
    bf16x8 pf[2];
#pragma unroll
    for (int ks = 0; ks < 2; ++ks)
      pf[ks] = *(const bf16x8*)(&sP[wave][rt * 72 + ks * 32 + kg * 8]);
#pragma unroll
    for (int n0 = 0; n0 < 8; ++n0) {
      const int brow = n0 * 16 + rt;
      f32x4 acc = o[n0];
#pragma unroll
      for (int ks = 0; ks < 2; ++ks) {
        bf16x8 vf = *(const bf16x8*)(&sV[brow * 64 + (((ks * 4 + kg) ^ (rt & 7)) * 8)]);
        acc = mfma16(pf[ks], vf, acc);
      }
      o[n0] = acc;
    }
  }
  // epilogue: center = x + O/l  (bf16 for FFN input)
  float il[4];
#pragma unroll
  for (int r = 0; r < 4; ++r) il[r] = 1.f / l[r];
  const size_t trow = tq0 + wave * 16 + kg * 4;
#pragma unroll
  for (int n0 = 0; n0 < 8; ++n0) {
    int col = n0 * 16 + rt;
#pragma unroll
    for (int r = 0; r < 4; ++r) {
      float val = o[n0][r] * il[r] + x[(trow + r) * 128 + col];
      center[(trow + r) * 128 + col] = (bf16_t)val;
    }
  }
}

// ---------------------------------------------------------------------------
// K4: mean_abs finalize, softmax over NV=64, top-8 hard routing, pi output,
// vertex_ctx -> boundary signal (all fp32). 64 tokens/block, 4 lanes/token.
// ---------------------------------------------------------------------------
__global__ __launch_bounds__(256) void k_pi(
    const float* __restrict__ x, const float* __restrict__ vs,
    const float* __restrict__ psum, const float* __restrict__ vemb,
    const float* __restrict__ v2h,
    float* __restrict__ pi_out, bf16_t* __restrict__ bound) {
  __shared__ float red[256];
  __shared__ float sVE[64 * 33];
  __shared__ float sV2H[128 * 33];
  const int tid = threadIdx.x;
  const int t0 = blockIdx.x * 64;
  red[tid] = psum[tid];
  for (int i = tid; i < 2048; i += 256) sVE[(i >> 5) * 33 + (i & 31)] = vemb[i];
  for (int i = tid; i < 4096; i += 256) sV2H[(i >> 5) * 33 + (i & 31)] = v2h[i];
  __syncthreads();
#pragma unroll
  for (int s = 128; s > 0; s >>= 1) {
    if (tid < s) red[tid] += red[tid + s];
    __syncthreads();
  }
  float mean_abs = fmaxf(red[0] * (1.f / 1048576.f), 1e-6f);
  float s3 = 3.f / mean_abs;

  const int tok = tid >> 2, part = tid & 3;
  const int tg = t0 + tok;
  const float* vr = vs + (size_t)tg * 64 + part * 16;
  float lg[16];
  float mx = -INFINITY;
#pragma unroll
  for (int j4 = 0; j4 < 4; ++j4) {
    float4 f = ((const float4*)vr)[j4];
    lg[j4 * 4 + 0] = f.x * s3; lg[j4 * 4 + 1] = f.y * s3;
    lg[j4 * 4 + 2] = f.z * s3; lg[j4 * 4 + 3] = f.w * s3;
    mx = fmaxf(mx, fmaxf(fmaxf(lg[j4 * 4 + 0], lg[j4 * 4 + 1]),
                         fmaxf(lg[j4 * 4 + 2], lg[j4 * 4 + 3])));
  }
  mx = fmaxf(mx, __shfl_xor(mx, 1));
  mx = fmaxf(mx, __shfl_xor(mx, 2));
  float e[16];
  float tot = 0.f;
#pragma unroll
  for (int j = 0; j < 16; ++j) { e[j] = expf(lg[j] - mx); tot += e[j]; }
  tot += __shfl_xor(tot, 1); tot += __shfl_xor(tot, 2);

  unsigned used = 0u;
  float tsum = 0.f;
#pragma unroll
  for (int it = 0; it < 8; ++it) {
    float bv = -INFINITY;
    int bi = 0;
#pragma unroll
    for (int j = 0; j < 16; ++j) {
      bool ok = !(used & (1u << j)) && (e[j] > bv);
      bv = ok ? e[j] : bv;
      bi = ok ? j : bi;
    }
    int gi = part * 16 + bi;
#pragma unroll
    for (int dm = 1; dm <= 2; dm <<= 1) {
      float ov = __shfl_xor(bv, dm);
      int oi = __shfl_xor(gi, dm);
      bool take = (ov > bv) || (ov == bv && oi < gi);
      bv = take ? ov : bv;
      gi = take ? oi : gi;
    }
    tsum += bv;
    if ((gi >> 4) == part) used |= 1u << (gi & 15);
  }
  float inv_tot = 1.f / tot;
  float inv_d = 1.f / (tsum * inv_tot + 1e-8f);
  float pi[16];
#pragma unroll
  for (int j = 0; j < 16; ++j)
    pi[j] = (used & (1u << j)) ? e[j] * inv_tot * inv_d : 0.f;
  float* po = pi_out + (size_t)tg * 64 + part * 16;
#pragma unroll
  for (int j4 = 0; j4 < 4; ++j4) {
    float4 f;
    f.x = pi[j4 * 4 + 0]; f.y = pi[j4 * 4 + 1];
    f.z = pi[j4 * 4 + 2]; f.w = pi[j4 * 4 + 3];
    ((float4*)po)[j4] = f;
  }
  float vc[32];
#pragma unroll
  for (int vv = 0; vv < 32; ++vv) vc[vv] = 0.f;
#pragma unroll
  for (int j = 0; j < 16; ++j) {
    float p = pi[j];
    int s = part * 16 + j;
#pragma unroll
    for (int vv = 0; vv < 32; ++vv) vc[vv] += p * sVE[s * 33 + vv];
  }
#pragma unroll
  for (int vv = 0; vv < 32; ++vv) {
    vc[vv] += __shfl_xor(vc[vv], 1);
    vc[vv] += __shfl_xor(vc[vv], 2);
  }
  const float* xr = x + (size_t)tg * 128 + part * 32;
  bf16_t* br = bound + (size_t)tg * 128 + part * 32;
#pragma unroll
  for (int d8 = 0; d8 < 4; ++d8) {
    float4 xa = ((const float4*)xr)[d8 * 2];
    float4 xb = ((const float4*)xr)[d8 * 2 + 1];
    float xv[8] = {xa.x, xa.y, xa.z, xa.w, xb.x, xb.y, xb.z, xb.w};
    bf16x8 ov;
#pragma unroll
    for (int k = 0; k < 8; ++k) {
      int d = part * 32 + d8 * 8 + k;
      float a = 0.f;
#pragma unroll
      for (int vv = 0; vv < 32; ++vv) a += vc[vv] * sV2H[d * 33 + vv];
      ov[k] = (bf16_t)(xv[k] + a);
    }
    *(bf16x8*)(br + d8 * 8) = ov;
  }
}

// ---------------------------------------------------------------------------
// K5: field FFN. phi = concat(center,bound)@pc^T + b; LN; gelu(phi_h@pu^T+b)@pd^T
//     + b + phi. 64 tokens/block, 4 waves. Weights via fragment-major global.
// ---------------------------------------------------------------------------
__global__ __launch_bounds__(256) void k_ffn(
    const bf16_t* __restrict__ center, const bf16_t* __restrict__ bound,
    const bf16_t* __restrict__ wf,
    const float* __restrict__ pc_b, const float* __restrict__ pn_g,
    const float* __restrict__ pn_b, const float* __restrict__ pu_b,
    const float* __restrict__ pd_b, float* __restrict__ out) {
  __shared__ __align__(16) bf16_t sH[64 * 128];   // phi_h (swizzled bytes)
  __shared__ __align__(16) bf16_t sG[64 * 256];   // gelu acts (swizzled bytes)
  const bf16_t* wpc = wf + 49152;
  const bf16_t* wpu = wf + 81920;
  const bf16_t* wpd = wf + 114688;
  const int tid = threadIdx.x;
  const int t0 = blockIdx.x * 64;
  const int wave = tid >> 6, lane = tid & 63;
  const int rt = lane & 15, kg = lane >> 4;
  const int arow = wave * 16 + rt;

  // phase A: phi = concat @ pc_w^T + pc_b  (A-frags straight from global)
  bf16x8 af[8];
#pragma unroll
  for (int ks = 0; ks < 8; ++ks) {
    const bf16_t* src = (ks < 4)
        ? (center + (size_t)(t0 + arow) * 128 + ks * 32 + kg * 8)
        : (bound + (size_t)(t0 + arow) * 128 + (ks - 4) * 32 + kg * 8);
    af[ks] = *(const bf16x8*)src;
  }
  f32x4 phi[8];
#pragma unroll
  for (int n0 = 0; n0 < 8; ++n0) {
    f32x4 acc = {0.f, 0.f, 0.f, 0.f};
#pragma unroll
    for (int ks = 0; ks < 8; ++ks) {
      bf16x8 bf = *(const bf16x8*)(wpc + ((size_t)(n0 * 8 + ks) * 64 + lane) * 8);
      acc = mfma16(af[ks], bf, acc);
    }
    float bias = pc_b[n0 * 16 + rt];
    acc[0] += bias; acc[1] += bias; acc[2] += bias; acc[3] += bias;
    phi[n0] = acc;
  }
  // LN over 128 cols (rows = kg*4+r, cols spread over rt lanes)
  float mean[4], rstd[4];
#pragma unroll
  for (int r = 0; r < 4; ++r) {
    float s0 = 0.f, s1 = 0.f;
#pragma unroll
    for (int n0 = 0; n0 < 8; ++n0) {
      float vv = phi[n0][r];
      s0 += vv; s1 += vv * vv;
    }
#pragma unroll
    for (int dm = 1; dm <= 8; dm <<= 1) {
      s0 += __shfl_xor(s0, dm);
      s1 += __shfl_xor(s1, dm);
    }
    mean[r] = s0 * (1.f / 128.f);
    float var = s1 * (1.f / 128.f) - mean[r] * mean[r];
    rstd[r] = rsqrtf(var + EPS_LN);
  }
#pragma unroll
  for (int n0 = 0; n0 < 8; ++n0) {
    int col = n0 * 16 + rt;
    float g = pn_g[col], bb = pn_b[col];
#pragma unroll
    for (int r = 0; r < 4; ++r) {
      float hv = (phi[n0][r] - mean[r]) * rstd[r] * g + bb;
      int row = wave * 16 + kg * 4 + r;
      *(bf16_t*)((char*)sH + row * 256 + ((2 * col) ^ ((row & 7) << 4))) = (bf16_t)hv;
    }
  }
  __syncthreads();

  // phase B: u = phi_h @ pu_w^T + pu_b ; gelu exact -> sG
  bf16x8 ah[4];
#pragma unroll
  for (int ks = 0; ks < 4; ++ks)
    ah[ks] = *(const bf16x8*)((const char*)sH + arow * 256 +
                              (((ks * 4 + kg) ^ (rt & 7)) * 16));
#pragma unroll
  for (int half = 0; half < 2; ++half) {
#pragma unroll
    for (int n0h = 0; n0h < 8; ++n0h) {
      int n0 = half * 8 + n0h;
      f32x4 acc = {0.f, 0.f, 0.f, 0.f};
#pragma unroll
      for (int ks = 0; ks < 4; ++ks) {
        bf16x8 bf = *(const bf16x8*)(wpu + ((size_t)(n0 * 4 + ks) * 64 + lane) * 8);
        acc = mfma16(ah[ks], bf, acc);
      }
      int col = n0 * 16 + rt;
      float bias = pu_b[col];
#pragma unroll
      for (int r = 0; r < 4; ++r) {
        float uv = acc[r] + bias;
        float gv = 0.5f * uv * (1.f + erff(uv * 0.7071067811865476f));
        int row = wave * 16 + kg * 4 + r;
        *(bf16_t*)((char*)sG + row * 512 + ((2 * col) ^ ((row & 7) << 4))) = (bf16_t)gv;
      }
    }
  }
  __syncthreads();

  // phase C: out = gelu @ pd_w^T + pd_b + phi
  bf16x8 ag[8];
#pragma unroll
  for (int ks = 0; ks < 8; ++ks)
    ag[ks] = *(const bf16x8*)((const char*)sG + arow * 512 +
                              (((ks * 4 + kg) ^ (rt & 7)) * 16));
#pragma unroll
  for (int n0 = 0; n0 < 8; ++n0) {
    f32x4 acc = {0.f, 0.f, 0.f, 0.f};
#pragma unroll
    for (int ks = 0; ks < 8; ++ks) {
      bf16x8 bf = *(const bf16x8*)(wpd + ((size_t)(n0 * 8 + ks) * 64 + lane) * 8);
      acc = mfma16(ag[ks], bf, acc);
    }
    float bias = pd_b[n0 * 16 + rt];
#pragma unroll
    for (int r = 0; r < 4; ++r) {
      int row = wave * 16 + kg * 4 + r;
      out[(size_t)(t0 + row) * 128 + n0 * 16 + rt] = acc[r] + bias + phi[n0][r];
    }
  }
}

// ---------------------------------------------------------------------------
extern "C" void kernel_launch(void* const* d_in, const int* in_sizes, int n_in,
                              void* d_out, int out_size, void* d_ws, size_t ws_size,
                              hipStream_t stream) {
  (void)in_sizes; (void)n_in; (void)out_size; (void)ws_size;
  const float* x     = (const float*)d_in[0];
  const float* gate  = (const float*)d_in[1];
  const float* mask  = (const float*)d_in[2];
  const float* nb6   = (const float*)d_in[3];
  const float* vemb  = (const float*)d_in[4];
  const float* adj   = (const float*)d_in[5];
  const float* spec  = (const float*)d_in[6];
  const float* wspec = (const float*)d_in[7];
  const float* cn_g  = (const float*)d_in[8];
  const float* cn_b  = (const float*)d_in[9];
  const float* Wq    = (const float*)d_in[10];
  const float* Wk    = (const float*)d_in[11];
  const float* Wv    = (const float*)d_in[12];
  const float* bn_g  = (const float*)d_in[13];
  const float* bn_b  = (const float*)d_in[14];
  const float* Wg_w  = (const float*)d_in[15];
  const float* Wg_b  = (const float*)d_in[16];
  const float* g2v   = (const float*)d_in[17];
  const float* v2h   = (const float*)d_in[18];
  const float* pc_w  = (const float*)d_in[19];
  const float* pc_b  = (const float*)d_in[20];
  const float* pn_g  = (const float*)d_in[21];
  const float* pn_b  = (const float*)d_in[22];
  const float* pu_w  = (const float*)d_in[23];
  const float* pu_b  = (const float*)d_in[24];
  const float* pd_w  = (const float*)d_in[25];
  const float* pd_b  = (const float*)d_in[26];

  char* ws = (char*)d_ws;
  bf16_t* Qb   = (bf16_t*)(ws);
  bf16_t* Kb   = (bf16_t*)(ws + (4u << 20));
  bf16_t* Vt   = (bf16_t*)(ws + (8u << 20));
  bf16_t* bnd  = (bf16_t*)(ws + (12u << 20));
  bf16_t* ctr  = (bf16_t*)(ws + (16u << 20));
  float*  vsc  = (float*)(ws + (20u << 20));
  float*  psum = (float*)(ws + (24u << 20));
  bf16_t* wfb  = (bf16_t*)(ws + (24u << 20) + 4096);

  float* f_out = (float*)d_out;                       // field [BT,128]
  float* pi_o  = f_out + (size_t)BT_ * 128;           // pi [BT,64]
  float* al_o  = pi_o + (size_t)BT_ * 64;             // alignment [B,T,T]

  k_prep<<<72, 256, 0, stream>>>(Wq, Wk, Wv, pc_w, pu_w, pd_w, wfb);
  k_qkv<<<256, 256, 0, stream>>>(x, gate, cn_g, cn_b, wfb, Qb, Kb, Vt);
  k_vscores<<<256, 256, 0, stream>>>(x, bn_g, bn_b, Wg_w, Wg_b, nb6, g2v, vemb,
                                     adj, spec, wspec, vsc, psum);
  k_attn<<<256, 256, 0, stream>>>(Qb, Kb, Vt, x, mask, al_o, ctr);
  k_pi<<<256, 256, 0, stream>>>(x, vsc, psum, vemb, v2h, pi_o, bnd);
  k_ffn<<<256, 256, 0, stream>>>(ctr, bnd, wfb, pc_b, pn_g, pn_b, pu_b, pd_b, f_out);
}

// Round 3
// 360.827 us; speedup vs baseline: 1.0709x; 1.0709x over previous
//
#include <hip/hip_runtime.h>
#include <cmath>

typedef __bf16 bf16_t;
typedef bf16_t bf16x8 __attribute__((ext_vector_type(8)));
typedef bf16_t bf16x4 __attribute__((ext_vector_type(4)));
typedef float f32x4 __attribute__((ext_vector_type(4)));

#define DEVI static __device__ __forceinline__

constexpr int TB = 8;        // batch
constexpr int TT = 2048;     // seq len
constexpr int BT_ = TB * TT; // tokens
constexpr float EPS_LN = 1e-5f;

DEVI f32x4 mfma16(bf16x8 a, bf16x8 b, f32x4 c) {
  return __builtin_amdgcn_mfma_f32_16x16x32_bf16(a, b, c, 0, 0, 0);
}

DEVI bf16x8 cvt8(float4 a, float4 b) {
  bf16x8 v;
  v[0] = (bf16_t)a.x; v[1] = (bf16_t)a.y; v[2] = (bf16_t)a.z; v[3] = (bf16_t)a.w;
  v[4] = (bf16_t)b.x; v[5] = (bf16_t)b.y; v[6] = (bf16_t)b.z; v[7] = (bf16_t)b.w;
  return v;
}

DEVI void gload_lds16(const void* g, void* l) {
  __builtin_amdgcn_global_load_lds(
      (const __attribute__((address_space(1))) unsigned int*)g,
      (__attribute__((address_space(3))) unsigned int*)l, 16, 0, 0);
}

// ---------------------------------------------------------------------------
// K0: pre-pack all MFMA weights f32 -> bf16 in fragment-major layout.
// Order in wf: Wq(16384) Wk(16384) Wv(16384) pc(32768) pu(32768) pd(32768)
// ---------------------------------------------------------------------------
__global__ __launch_bounds__(256) void k_prep(
    const float* __restrict__ Wq, const float* __restrict__ Wk,
    const float* __restrict__ Wv, const float* __restrict__ Wpc,
    const float* __restrict__ Wpu, const float* __restrict__ Wpd,
    bf16_t* __restrict__ wf) {
  int g = blockIdx.x * 256 + threadIdx.x;   // 18432 fragment-groups total
  const float* W;
  bf16_t* dst;
  int rel, lks, Kdim;
  if (g < 6144) {                 // Wq/Wk/Wv: 128x128, KS=4
    int m = g >> 11; rel = g & 2047;
    W = (m == 0) ? Wq : ((m == 1) ? Wk : Wv);
    dst = wf + m * 16384; lks = 2; Kdim = 128;
  } else if (g < 10240) {         // pc_w: 128x256, KS=8
    rel = g - 6144; W = Wpc; dst = wf + 49152; lks = 3; Kdim = 256;
  } else if (g < 14336) {         // pu_w: 256x128, KS=4
    rel = g - 10240; W = Wpu; dst = wf + 81920; lks = 2; Kdim = 128;
  } else {                        // pd_w: 128x256, KS=8
    rel = g - 14336; W = Wpd; dst = wf + 114688; lks = 3; Kdim = 256;
  }
  int lane = rel & 63;
  int fk = (rel >> 6) & ((1 << lks) - 1);
  int n0 = rel >> (6 + lks);
  int row = n0 * 16 + (lane & 15);
  int col = fk * 32 + (lane >> 4) * 8;
  const float* s = W + row * Kdim + col;
  float4 a = *(const float4*)s;
  float4 b = *(const float4*)(s + 4);
  *(bf16x8*)(dst + (size_t)rel * 8) = cvt8(a, b);
}

// ---------------------------------------------------------------------------
// K1: LN(cn) + Q/K/V projections (gate on Q,K). 64 tokens, 4 waves.
// grid 512: sel=blockIdx>>8 splits outputs (sel0: Q + V[0..3]; sel1: K + V[4..7])
// so 2 blocks/CU -> 8 waves/CU. LN recomputed per block (cheap).
// ---------------------------------------------------------------------------
__global__ __launch_bounds__(256) void k_qkv(
    const float* __restrict__ x, const float* __restrict__ gate,
    const float* __restrict__ cn_g, const float* __restrict__ cn_b,
    const bf16_t* __restrict__ wf,
    bf16_t* __restrict__ Qo, bf16_t* __restrict__ Ko, bf16_t* __restrict__ Vt) {
  __shared__ __align__(16) bf16_t sH[64 * 128];   // swizzled 16B blocks
  const int tid = threadIdx.x;
  const int sel = blockIdx.x >> 8;
  const int t0 = (blockIdx.x & 255) * 64;

  { // LayerNorm: 4 threads per token, 32 elems each
    const int tok = tid >> 2, part = tid & 3;
    const float* xr = x + (size_t)(t0 + tok) * 128 + part * 32;
    float v[32];
    float s0 = 0.f, s1 = 0.f;
#pragma unroll
    for (int i = 0; i < 8; ++i) {
      float4 f = ((const float4*)xr)[i];
      v[i * 4 + 0] = f.x; v[i * 4 + 1] = f.y; v[i * 4 + 2] = f.z; v[i * 4 + 3] = f.w;
      s0 += f.x + f.y + f.z + f.w;
      s1 += f.x * f.x + f.y * f.y + f.z * f.z + f.w * f.w;
    }
    s0 += __shfl_xor(s0, 1); s0 += __shfl_xor(s0, 2);
    s1 += __shfl_xor(s1, 1); s1 += __shfl_xor(s1, 2);
    float mean = s0 * (1.f / 128.f);
    float var = s1 * (1.f / 128.f) - mean * mean;
    float rstd = rsqrtf(var + EPS_LN);
#pragma unroll
    for (int j8 = 0; j8 < 4; ++j8) {
      bf16x8 hv;
#pragma unroll
      for (int k = 0; k < 8; ++k) {
        int d = part * 32 + j8 * 8 + k;
        float hn = (v[j8 * 8 + k] - mean) * rstd;
        hv[k] = (bf16_t)(hn * cn_g[d] + cn_b[d]);
      }
      int bl = part * 4 + j8;
      *(bf16x8*)(&sH[tok * 128 + ((bl ^ (tok & 7)) * 8)]) = hv;
    }
  }
  __syncthreads();

  const int wave = tid >> 6, lane = tid & 63;
  const int rt = lane & 15, kg = lane >> 4;
  const int arow = wave * 16 + rt;
  bf16x8 af[4];
#pragma unroll
  for (int ks = 0; ks < 4; ++ks)
    af[ks] = *(const bf16x8*)(&sH[arow * 128 + (((ks * 4 + kg) ^ (rt & 7)) * 8)]);

  const int trow0 = t0 + wave * 16 + kg * 4;  // first of 4 output token rows
  float4 g4 = *(const float4*)(gate + trow0);
  float gr[4] = {g4.x, g4.y, g4.z, g4.w};
  const int b_ = trow0 >> 11;
  const int tloc = trow0 & 2047;

  // Q (sel=0) or K (sel=1), gated
  {
    const bf16_t* wm = wf + sel * 16384;
    bf16_t* O = sel ? Ko : Qo;
#pragma unroll
    for (int n0 = 0; n0 < 8; ++n0) {
      f32x4 acc = {0.f, 0.f, 0.f, 0.f};
#pragma unroll
      for (int ks = 0; ks < 4; ++ks) {
        bf16x8 bf = *(const bf16x8*)(wm + ((size_t)(n0 * 4 + ks) * 64 + lane) * 8);
        acc = mfma16(af[ks], bf, acc);
      }
#pragma unroll
      for (int r = 0; r < 4; ++r)
        O[(size_t)(trow0 + r) * 128 + n0 * 16 + rt] = (bf16_t)(acc[r] * gr[r]);
    }
  }
  // V half (transposed store)
  {
    const bf16_t* wv = wf + 2 * 16384;
#pragma unroll
    for (int n0h = 0; n0h < 4; ++n0h) {
      int n0 = sel * 4 + n0h;
      f32x4 acc = {0.f, 0.f, 0.f, 0.f};
#pragma unroll
      for (int ks = 0; ks < 4; ++ks) {
        bf16x8 bf = *(const bf16x8*)(wv + ((size_t)(n0 * 4 + ks) * 64 + lane) * 8);
        acc = mfma16(af[ks], bf, acc);
      }
      bf16x4 pk;
      pk[0] = (bf16_t)acc[0]; pk[1] = (bf16_t)acc[1];
      pk[2] = (bf16_t)acc[2]; pk[3] = (bf16_t)acc[3];
      *(bf16x4*)(Vt + ((size_t)(b_ * 128 + n0 * 16 + rt)) * 2048 + tloc) = pk;
    }
  }
}

// ---------------------------------------------------------------------------
// K2: boundary v_scores (all fp32 vector math) + per-block |.| partial sums.
// ---------------------------------------------------------------------------
__global__ __launch_bounds__(256) void k_vscores(
    const float* __restrict__ x, const float* __restrict__ bn_g,
    const float* __restrict__ bn_b, const float* __restrict__ Wg_w,
    const float* __restrict__ Wg_b, const float* __restrict__ nb6,
    const float* __restrict__ g2v, const float* __restrict__ vemb,
    const float* __restrict__ adj, const float* __restrict__ spec,
    const float* __restrict__ wspec,
    float* __restrict__ vs_out, float* __restrict__ psum) {
  __shared__ float sWg[768];
  __shared__ float sG2V[192];
  __shared__ float sVE[64 * 33];
  __shared__ float sSP[64 * 33];
  __shared__ float sADJ[64 * 64];
  __shared__ float sRaw[64 * 68];
  __shared__ float sBN[256];
  __shared__ float bsum;
  const int tid = threadIdx.x;
  const int t0 = blockIdx.x * 64;
  if (tid == 0) bsum = 0.f;
  for (int i = tid; i < 768; i += 256) sWg[i] = Wg_w[i];
  for (int i = tid; i < 192; i += 256) sG2V[i] = g2v[i];
  for (int i = tid; i < 256; i += 256) sBN[i] = (i < 128) ? bn_g[i] : bn_b[i - 128];
  for (int i = tid; i < 2048; i += 256) sVE[(i >> 5) * 33 + (i & 31)] = vemb[i];
  for (int i = tid; i < 4096; i += 256) sADJ[i] = adj[i];
  for (int i = tid; i < 2048; i += 256) {
    int s = i >> 5, vv = i & 31;
    float acc = 0.f;
#pragma unroll
    for (int e = 0; e < 16; ++e) acc += spec[s * 16 + e] * wspec[vv * 16 + e];
    sSP[s * 33 + vv] = acc;
  }
  __syncthreads();

  const int tok = tid >> 2, part = tid & 3;
  const float* xr = x + (size_t)(t0 + tok) * 128 + part * 32;
  float v[32];
  float s0 = 0.f, s1 = 0.f;
#pragma unroll
  for (int i = 0; i < 8; ++i) {
    float4 f = ((const float4*)xr)[i];
    v[i * 4 + 0] = f.x; v[i * 4 + 1] = f.y; v[i * 4 + 2] = f.z; v[i * 4 + 3] = f.w;
    s0 += f.x + f.y + f.z + f.w;
    s1 += f.x * f.x + f.y * f.y + f.z * f.z + f.w * f.w;
  }
  s0 += __shfl_xor(s0, 1); s0 += __shfl_xor(s0, 2);
  s1 += __shfl_xor(s1, 1); s1 += __shfl_xor(s1, 2);
  float mean = s0 * (1.f / 128.f);
  float rstd = rsqrtf(s1 * (1.f / 128.f) - mean * mean + EPS_LN);
  float hb[32];
#pragma unroll
  for (int k = 0; k < 32; ++k) {
    int d = part * 32 + k;
    hb[k] = (v[k] - mean) * rstd * sBN[d] + sBN[128 + d];
  }
  float g6[6];
#pragma unroll
  for (int j = 0; j < 6; ++j) {
    float a = 0.f;
#pragma unroll
    for (int k = 0; k < 32; ++k) a += hb[k] * sWg[j * 128 + part * 32 + k];
    a += __shfl_xor(a, 1); a += __shfl_xor(a, 2);
    a += Wg_b[j] + nb6[j];
    g6[j] = 1.f / (1.f + __expf(-a));
  }
  float gp[32];
#pragma unroll
  for (int vv = 0; vv < 32; ++vv) {
    float a = 0.f;
#pragma unroll
    for (int j = 0; j < 6; ++j) a += g6[j] * sG2V[vv * 6 + j];
    gp[vv] = a;
  }
#pragma unroll
  for (int j = 0; j < 16; ++j) {
    int s = part * 16 + j;
    float a = 0.f;
#pragma unroll
    for (int vv = 0; vv < 32; ++vv)
      a += gp[vv] * (sVE[s * 33 + vv] + 0.1f * sSP[s * 33 + vv]);
    sRaw[tok * 68 + s] = a;
  }
  __syncthreads();

  float fin[16];
#pragma unroll
  for (int j = 0; j < 16; ++j) fin[j] = 0.f;
  for (int s = 0; s < 64; ++s) {
    float rv = sRaw[tok * 68 + s];
#pragma unroll
    for (int j = 0; j < 16; ++j) fin[j] += rv * sADJ[s * 64 + part * 16 + j];
  }
  float sa = 0.f;
#pragma unroll
  for (int j = 0; j < 16; ++j) {
    fin[j] = sRaw[tok * 68 + part * 16 + j] + 0.1f * fin[j];
    sa += fabsf(fin[j]);
  }
  float* o = vs_out + (size_t)(t0 + tok) * 64 + part * 16;
#pragma unroll
  for (int j4 = 0; j4 < 4; ++j4) {
    float4 f;
    f.x = fin[j4 * 4 + 0]; f.y = fin[j4 * 4 + 1];
    f.z = fin[j4 * 4 + 2]; f.w = fin[j4 * 4 + 3];
    ((float4*)o)[j4] = f;
  }
#pragma unroll
  for (int m = 1; m <= 32; m <<= 1) sa += __shfl_xor(sa, m);
  if ((tid & 63) == 0) atomicAdd(&bsum, sa);
  __syncthreads();
  if (tid == 0) psum[blockIdx.x] = bsum;
}

// ---------------------------------------------------------------------------
// K3: flash attention + alignment output. Split-S across nsplit blocks
// (partials o,m,l to ws; k_comb merges). Double-buffered K/V staging via
// global_load_lds so the next tile's loads overlap current compute.
// grid = 256*nsplit; LDS 73 KB -> 2 blocks/CU when nsplit>=2.
// ---------------------------------------------------------------------------
__global__ __launch_bounds__(256) void k_attn(
    const bf16_t* __restrict__ Q, const bf16_t* __restrict__ Kp,
    const bf16_t* __restrict__ Vt, const float* __restrict__ x,
    const float* __restrict__ mask, float* __restrict__ align_out,
    bf16_t* __restrict__ center, float* __restrict__ o_part,
    float* __restrict__ ml_part, int nsplit) {
  __shared__ __align__(16) bf16_t sK[2][64 * 128];
  __shared__ __align__(16) bf16_t sV[2][128 * 64];
  __shared__ __align__(16) bf16_t sP[4][16 * 72];   // +8 pad per row
  const int tid = threadIdx.x;
  const int b_ = blockIdx.x & 7;          // XCD-affine batch
  const int qt = (blockIdx.x >> 3) & 31;
  const int sq = blockIdx.x >> 8;
  const int ntile = 32 / nsplit;
  const int st0 = sq * ntile;
  const int wave = tid >> 6, lane = tid & 63;
  const int rt = lane & 15, kg = lane >> 4;
  const size_t tq0 = (size_t)b_ * TT + qt * 64;

  bf16x8 qf[4];
#pragma unroll
  for (int ks = 0; ks < 4; ++ks)
    qf[ks] = *(const bf16x8*)(Q + (tq0 + wave * 16 + rt) * 128 + ks * 32 + kg * 8);

  f32x4 o[8];
  f32x4 zero4 = {0.f, 0.f, 0.f, 0.f};
#pragma unroll
  for (int i = 0; i < 8; ++i) o[i] = zero4;
  float m[4], l[4];
#pragma unroll
  for (int r = 0; r < 4; ++r) { m[r] = -INFINITY; l[r] = 0.f; }
  const float inv_sc = 0.08838834764831845f;  // 1/sqrt(128)
  const int tqr = qt * 64 + wave * 16 + kg * 4;
  const int koff = wave * 1024 + lane * 16;

  auto stage = [&](int buf, int st) {
    const int sb2 = st * 64;
#pragma unroll
    for (int i = 0; i < 4; ++i) {
      int off = i * 4096 + koff;
      int row = off >> 8;
      int c16 = (off >> 4) & 15;
      const char* src = (const char*)Kp +
          ((size_t)(b_ * TT + sb2 + row) * 128 + ((c16 ^ (row & 7)) * 8)) * 2;
      gload_lds16(src, (char*)(&sK[buf][0]) + i * 4096 + wave * 1024);
    }
#pragma unroll
    for (int i = 0; i < 4; ++i) {
      int off = i * 4096 + koff;
      int row = off >> 7;
      int c16 = (off >> 4) & 7;
      const char* src = (const char*)Vt +
          ((size_t)(b_ * 128 + row) * 2048 + sb2 + ((c16 ^ (row & 7)) * 8)) * 2;
      gload_lds16(src, (char*)(&sV[buf][0]) + i * 4096 + wave * 1024);
    }
  };

  int cur = 0;
  stage(0, st0);
  for (int it = 0; it < ntile; ++it) {
    const int sb = (st0 + it) * 64;
    __syncthreads();   // drains stage(cur) (vmcnt 0) + prior-iter LDS reads done
    if (it + 1 < ntile) stage(cur ^ 1, st0 + it + 1);  // prefetch overlaps compute

    // scores S = Q K^T / sqrt(D) + mask ; write alignment; online softmax
    float p[4][4];
#pragma unroll
    for (int ct = 0; ct < 4; ++ct) {
      const int brow = ct * 16 + rt;
      f32x4 acc = zero4;
#pragma unroll
      for (int ks = 0; ks < 4; ++ks) {
        bf16x8 kf = *(const bf16x8*)(&sK[cur][brow * 128 + (((ks * 4 + kg) ^ (rt & 7)) * 8)]);
        acc = mfma16(qf[ks], kf, acc);
      }
      const int scol = sb + ct * 16 + rt;
#pragma unroll
      for (int r = 0; r < 4; ++r) {
        float sv = acc[r] * inv_sc + mask[(size_t)(tqr + r) * TT + scol];
        align_out[((size_t)b_ * TT + tqr + r) * TT + scol] = sv;
        p[ct][r] = sv;
      }
    }
    float mn[4], fsc[4];
#pragma unroll
    for (int r = 0; r < 4; ++r) {
      float pm = fmaxf(fmaxf(p[0][r], p[1][r]), fmaxf(p[2][r], p[3][r]));
#pragma unroll
      for (int dm = 1; dm <= 8; dm <<= 1) pm = fmaxf(pm, __shfl_xor(pm, dm));
      mn[r] = fmaxf(m[r], pm);
      fsc[r] = __expf(m[r] - mn[r]);
      m[r] = mn[r];
    }
    float rs[4] = {0.f, 0.f, 0.f, 0.f};
#pragma unroll
    for (int ct = 0; ct < 4; ++ct)
#pragma unroll
      for (int r = 0; r < 4; ++r) {
        float pe = __expf(p[ct][r] - mn[r]);
        p[ct][r] = pe;
        rs[r] += pe;
      }
#pragma unroll
    for (int r = 0; r < 4; ++r) {
#pragma unroll
      for (int dm = 1; dm <= 8; dm <<= 1) rs[r] += __shfl_xor(rs[r], dm);
      l[r] = l[r] * fsc[r] + rs[r];
    }
#pragma unroll
    for (int i = 0; i < 8; ++i) {
      o[i][0] *= fsc[0]; o[i][1] *= fsc[1]; o[i][2] *= fsc[2]; o[i][3] *= fsc[3];
    }
    // P -> bf16 -> per-wave LDS (same-wave write->read, in-order DS)
#pragma unroll
    for (int ct = 0; ct < 4; ++ct)
#pragma unroll
      for (int r = 0; r < 4; ++r)
        sP[wave][(kg * 4 + r) * 72 + ct * 16 + rt] = (bf16_t)p[ct][r];
    asm volatile("" ::: "memory");
    bf16x8 pf[2];
#pragma unroll
    for (int ks = 0; ks < 2; ++ks)
      pf[ks] = *(const bf16x8*)(&sP[wave][rt * 72 + ks * 32 + kg * 8]);
#pragma unroll
    for (int n0 = 0; n0 < 8; ++n0) {
      const int brow = n0 * 16 + rt;
      f32x4 acc = o[n0];
#pragma unroll
      for (int ks = 0; ks < 2; ++ks) {
        bf16x8 vf = *(const bf16x8*)(&sV[cur][brow * 64 + (((ks * 4 + kg) ^ (rt & 7)) * 8)]);
        acc = mfma16(pf[ks], vf, acc);
      }
      o[n0] = acc;
    }
    cur ^= 1;
  }

  const size_t trow = tq0 + wave * 16 + kg * 4;
  if (nsplit == 1) {
    float il[4];
#pragma unroll
    for (int r = 0; r < 4; ++r) il[r] = 1.f / l[r];
#pragma unroll
    for (int n0 = 0; n0 < 8; ++n0) {
      int col = n0 * 16 + rt;
#pragma unroll
      for (int r = 0; r < 4; ++r) {
        float val = o[n0][r] * il[r] + x[(trow + r) * 128 + col];
        center[(trow + r) * 128 + col] = (bf16_t)val;
      }
    }
  } else {
#pragma unroll
    for (int n0 = 0; n0 < 8; ++n0) {
      int col = n0 * 16 + rt;
#pragma unroll
      for (int r = 0; r < 4; ++r)
        o_part[((size_t)sq * BT_ + trow + r) * 128 + col] = o[n0][r];
    }
    if (rt == 0) {
#pragma unroll
      for (int r = 0; r < 4; ++r) {
        size_t t = (size_t)sq * BT_ + trow + r;
        ml_part[t * 2] = m[r];
        ml_part[t * 2 + 1] = l[r];
      }
    }
  }
}

// ---------------------------------------------------------------------------
// K3b: merge split-S partials -> center = x + (sum_i o_i*w_i)/(sum_i l_i*w_i)
// ---------------------------------------------------------------------------
__global__ __launch_bounds__(256) void k_comb(
    const float* __restrict__ x, const float* __restrict__ o_part,
    const float* __restrict__ ml_part, bf16_t* __restrict__ center) {
  const int tid = threadIdx.x;
  const int tok = blockIdx.x * 64 + (tid >> 2);
  const int part = tid & 3;
  float m0 = ml_part[(size_t)tok * 2];
  float l0 = ml_part[(size_t)tok * 2 + 1];
  float m1 = ml_part[((size_t)BT_ + tok) * 2];
  float l1 = ml_part[((size_t)BT_ + tok) * 2 + 1];
  float M = fmaxf(m0, m1);
  float w0 = __expf(m0 - M), w1 = __expf(m1 - M);
  float inv = 1.f / (l0 * w0 + l1 * w1);
  w0 *= inv; w1 *= inv;
  const float* xr = x + (size_t)tok * 128 + part * 32;
  const float* o0 = o_part + (size_t)tok * 128 + part * 32;
  const float* o1 = o_part + ((size_t)BT_ + tok) * 128 + part * 32;
  bf16_t* cr = center + (size_t)tok * 128 + part * 32;
#pragma unroll
  for (int c = 0; c < 4; ++c) {
    float4 a0 = ((const float4*)(o0 + c * 8))[0];
    float4 b0 = ((const float4*)(o0 + c * 8))[1];
    float4 a1 = ((const float4*)(o1 + c * 8))[0];
    float4 b1 = ((const float4*)(o1 + c * 8))[1];
    float4 xa = ((const float4*)(xr + c * 8))[0];
    float4 xb = ((const float4*)(xr + c * 8))[1];
    bf16x8 ov;
    ov[0] = (bf16_t)(a0.x * w0 + a1.x * w1 + xa.x);
    ov[1] = (bf16_t)(a0.y * w0 + a1.y * w1 + xa.y);
    ov[2] = (bf16_t)(a0.z * w0 + a1.z * w1 + xa.z);
    ov[3] = (bf16_t)(a0.w * w0 + a1.w * w1 + xa.w);
    ov[4] = (bf16_t)(b0.x * w0 + b1.x * w1 + xb.x);
    ov[5] = (bf16_t)(b0.y * w0 + b1.y * w1 + xb.y);
    ov[6] = (bf16_t)(b0.z * w0 + b1.z * w1 + xb.z);
    ov[7] = (bf16_t)(b0.w * w0 + b1.w * w1 + xb.w);
    *(bf16x8*)(cr + c * 8) = ov;
  }
}

// ---------------------------------------------------------------------------
// K4: mean_abs finalize, softmax over NV=64, top-8 hard routing, pi output,
// vertex_ctx -> boundary signal (all fp32). 64 tokens/block, 4 lanes/token.
// ---------------------------------------------------------------------------
__global__ __launch_bounds__(256) void k_pi(
    const float* __restrict__ x, const float* __restrict__ vs,
    const float* __restrict__ psum, const float* __restrict__ vemb,
    const float* __restrict__ v2h,
    float* __restrict__ pi_out, bf16_t* __restrict__ bound) {
  __shared__ float red[256];
  __shared__ float sVE[64 * 33];
  __shared__ float sV2H[128 * 33];
  const int tid = threadIdx.x;
  const int t0 = blockIdx.x * 64;
  red[tid] = psum[tid];
  for (int i = tid; i < 2048; i += 256) sVE[(i >> 5) * 33 + (i & 31)] = vemb[i];
  for (int i = tid; i < 4096; i += 256) sV2H[(i >> 5) * 33 + (i & 31)] = v2h[i];
  __syncthreads();
#pragma unroll
  for (int s = 128; s > 0; s >>= 1) {
    if (tid < s) red[tid] += red[tid + s];
    __syncthreads();
  }
  float mean_abs = fmaxf(red[0] * (1.f / 1048576.f), 1e-6f);
  float s3 = 3.f / mean_abs;

  const int tok = tid >> 2, part = tid & 3;
  const int tg = t0 + tok;
  const float* vr = vs + (size_t)tg * 64 + part * 16;
  float lg[16];
  float mx = -INFINITY;
#pragma unroll
  for (int j4 = 0; j4 < 4; ++j4) {
    float4 f = ((const float4*)vr)[j4];
    lg[j4 * 4 + 0] = f.x * s3; lg[j4 * 4 + 1] = f.y * s3;
    lg[j4 * 4 + 2] = f.z * s3; lg[j4 * 4 + 3] = f.w * s3;
    mx = fmaxf(mx, fmaxf(fmaxf(lg[j4 * 4 + 0], lg[j4 * 4 + 1]),
                         fmaxf(lg[j4 * 4 + 2], lg[j4 * 4 + 3])));
  }
  mx = fmaxf(mx, __shfl_xor(mx, 1));
  mx = fmaxf(mx, __shfl_xor(mx, 2));
  float e[16];
  float tot = 0.f;
#pragma unroll
  for (int j = 0; j < 16; ++j) { e[j] = __expf(lg[j] - mx); tot += e[j]; }
  tot += __shfl_xor(tot, 1); tot += __shfl_xor(tot, 2);

  unsigned used = 0u;
  float tsum = 0.f;
#pragma unroll
  for (int it = 0; it < 8; ++it) {
    float bv = -INFINITY;
    int bi = 0;
#pragma unroll
    for (int j = 0; j < 16; ++j) {
      bool ok = !(used & (1u << j)) && (e[j] > bv);
      bv = ok ? e[j] : bv;
      bi = ok ? j : bi;
    }
    int gi = part * 16 + bi;
#pragma unroll
    for (int dm = 1; dm <= 2; dm <<= 1) {
      float ov = __shfl_xor(bv, dm);
      int oi = __shfl_xor(gi, dm);
      bool take = (ov > bv) || (ov == bv && oi < gi);
      bv = take ? ov : bv;
      gi = take ? oi : gi;
    }
    tsum += bv;
    if ((gi >> 4) == part) used |= 1u << (gi & 15);
  }
  float inv_tot = 1.f / tot;
  float inv_d = 1.f / (tsum * inv_tot + 1e-8f);
  float pi[16];
#pragma unroll
  for (int j = 0; j < 16; ++j)
    pi[j] = (used & (1u << j)) ? e[j] * inv_tot * inv_d : 0.f;
  float* po = pi_out + (size_t)tg * 64 + part * 16;
#pragma unroll
  for (int j4 = 0; j4 < 4; ++j4) {
    float4 f;
    f.x = pi[j4 * 4 + 0]; f.y = pi[j4 * 4 + 1];
    f.z = pi[j4 * 4 + 2]; f.w = pi[j4 * 4 + 3];
    ((float4*)po)[j4] = f;
  }
  float vc[32];
#pragma unroll
  for (int vv = 0; vv < 32; ++vv) vc[vv] = 0.f;
#pragma unroll
  for (int j = 0; j < 16; ++j) {
    float p = pi[j];
    int s = part * 16 + j;
#pragma unroll
    for (int vv = 0; vv < 32; ++vv) vc[vv] += p * sVE[s * 33 + vv];
  }
#pragma unroll
  for (int vv = 0; vv < 32; ++vv) {
    vc[vv] += __shfl_xor(vc[vv], 1);
    vc[vv] += __shfl_xor(vc[vv], 2);
  }
  const float* xr = x + (size_t)tg * 128 + part * 32;
  bf16_t* br = bound + (size_t)tg * 128 + part * 32;
#pragma unroll
  for (int d8 = 0; d8 < 4; ++d8) {
    float4 xa = ((const float4*)xr)[d8 * 2];
    float4 xb = ((const float4*)xr)[d8 * 2 + 1];
    float xv[8] = {xa.x, xa.y, xa.z, xa.w, xb.x, xb.y, xb.z, xb.w};
    bf16x8 ov;
#pragma unroll
    for (int k = 0; k < 8; ++k) {
      int d = part * 32 + d8 * 8 + k;
      float a = 0.f;
#pragma unroll
      for (int vv = 0; vv < 32; ++vv) a += vc[vv] * sV2H[d * 33 + vv];
      ov[k] = (bf16_t)(xv[k] + a);
    }
    *(bf16x8*)(br + d8 * 8) = ov;
  }
}

// ---------------------------------------------------------------------------
// K5: field FFN. 32 tokens/block, grid 512 (2 blocks/CU -> 8 waves/CU).
// 4 waves: g=wave&1 -> row group (16 rows), h=wave>>1 -> n0 half.
// Cross-wave LN partials exchanged via sLN.
// ---------------------------------------------------------------------------
__global__ __launch_bounds__(256) void k_ffn(
    const bf16_t* __restrict__ center, const bf16_t* __restrict__ bound,
    const bf16_t* __restrict__ wf,
    const float* __restrict__ pc_b, const float* __restrict__ pn_g,
    const float* __restrict__ pn_b, const float* __restrict__ pu_b,
    const float* __restrict__ pd_b, float* __restrict__ out) {
  __shared__ __align__(16) bf16_t sH[32 * 128];   // phi_h (swizzled bytes)
  __shared__ __align__(16) bf16_t sG[32 * 256];   // gelu acts (swizzled bytes)
  __shared__ float sLN[2][32][2];                 // [h][row][{s0,s1}]
  const bf16_t* wpc = wf + 49152;
  const bf16_t* wpu = wf + 81920;
  const bf16_t* wpd = wf + 114688;
  const int tid = threadIdx.x;
  const int t0 = blockIdx.x * 32;
  const int wave = tid >> 6, lane = tid & 63;
  const int g = wave & 1, h = wave >> 1;
  const int rt = lane & 15, kg = lane >> 4;
  const int arow = g * 16 + rt;

  // phase A: phi = concat @ pc_w^T + pc_b ; wave covers n0 in [4h, 4h+4)
  bf16x8 af[8];
#pragma unroll
  for (int ks = 0; ks < 8; ++ks) {
    const bf16_t* src = (ks < 4)
        ? (center + (size_t)(t0 + arow) * 128 + ks * 32 + kg * 8)
        : (bound + (size_t)(t0 + arow) * 128 + (ks - 4) * 32 + kg * 8);
    af[ks] = *(const bf16x8*)src;
  }
  f32x4 phi[4];
#pragma unroll
  for (int j = 0; j < 4; ++j) {
    int n0 = 4 * h + j;
    f32x4 acc = {0.f, 0.f, 0.f, 0.f};
#pragma unroll
    for (int ks = 0; ks < 8; ++ks) {
      bf16x8 bf = *(const bf16x8*)(wpc + ((size_t)(n0 * 8 + ks) * 64 + lane) * 8);
      acc = mfma16(af[ks], bf, acc);
    }
    float bias = pc_b[n0 * 16 + rt];
    acc[0] += bias; acc[1] += bias; acc[2] += bias; acc[3] += bias;
    phi[j] = acc;
  }
  // LN partials over this wave's 64 cols, rows g*16+kg*4+r
#pragma unroll
  for (int r = 0; r < 4; ++r) {
    float s0 = 0.f, s1 = 0.f;
#pragma unroll
    for (int j = 0; j < 4; ++j) {
      float vv = phi[j][r];
      s0 += vv; s1 += vv * vv;
    }
#pragma unroll
    for (int dm = 1; dm <= 8; dm <<= 1) {
      s0 += __shfl_xor(s0, dm);
      s1 += __shfl_xor(s1, dm);
    }
    if (rt == 0) {
      int row = g * 16 + kg * 4 + r;
      sLN[h][row][0] = s0;
      sLN[h][row][1] = s1;
    }
  }
  __syncthreads();
  float mean[4], rstd[4];
#pragma unroll
  for (int r = 0; r < 4; ++r) {
    int row = g * 16 + kg * 4 + r;
    float s0 = sLN[0][row][0] + sLN[1][row][0];
    float s1 = sLN[0][row][1] + sLN[1][row][1];
    mean[r] = s0 * (1.f / 128.f);
    float var = s1 * (1.f / 128.f) - mean[r] * mean[r];
    rstd[r] = rsqrtf(var + EPS_LN);
  }
#pragma unroll
  for (int j = 0; j < 4; ++j) {
    int col = (4 * h + j) * 16 + rt;
    float gg = pn_g[col], bb = pn_b[col];
#pragma unroll
    for (int r = 0; r < 4; ++r) {
      float hv = (phi[j][r] - mean[r]) * rstd[r] * gg + bb;
      int row = g * 16 + kg * 4 + r;
      *(bf16_t*)((char*)sH + row * 256 + ((2 * col) ^ ((row & 7) << 4))) = (bf16_t)hv;
    }
  }
  __syncthreads();

  // phase B: u = phi_h @ pu_w^T + pu_b ; gelu exact -> sG. wave: n0 in [8h, 8h+8)
  bf16x8 ah[4];
#pragma unroll
  for (int ks = 0; ks < 4; ++ks)
    ah[ks] = *(const bf16x8*)((const char*)sH + arow * 256 +
                              (((ks * 4 + kg) ^ (rt & 7)) * 16));
#pragma unroll
  for (int j2 = 0; j2 < 8; ++j2) {
    int n0 = 8 * h + j2;
    f32x4 acc = {0.f, 0.f, 0.f, 0.f};
#pragma unroll
    for (int ks = 0; ks < 4; ++ks) {
      bf16x8 bf = *(const bf16x8*)(wpu + ((size_t)(n0 * 4 + ks) * 64 + lane) * 8);
      acc = mfma16(ah[ks], bf, acc);
    }
    int col = n0 * 16 + rt;
    float bias = pu_b[col];
#pragma unroll
    for (int r = 0; r < 4; ++r) {
      float uv = acc[r] + bias;
      float gv = 0.5f * uv * (1.f + erff(uv * 0.7071067811865476f));
      int row = g * 16 + kg * 4 + r;
      *(bf16_t*)((char*)sG + row * 512 + ((2 * col) ^ ((row & 7) << 4))) = (bf16_t)gv;
    }
  }
  __syncthreads();

  // phase C: out = gelu @ pd_w^T + pd_b + phi. wave: n0 in [4h, 4h+4)
  bf16x8 ag[8];
#pragma unroll
  for (int ks = 0; ks < 8; ++ks)
    ag[ks] = *(const bf16x8*)((const char*)sG + arow * 512 +
                              (((ks * 4 + kg) ^ (rt & 7)) * 16));
#pragma unroll
  for (int j = 0; j < 4; ++j) {
    int n0 = 4 * h + j;
    f32x4 acc = {0.f, 0.f, 0.f, 0.f};
#pragma unroll
    for (int ks = 0; ks < 8; ++ks) {
      bf16x8 bf = *(const bf16x8*)(wpd + ((size_t)(n0 * 8 + ks) * 64 + lane) * 8);
      acc = mfma16(ag[ks], bf, acc);
    }
    float bias = pd_b[n0 * 16 + rt];
#pragma unroll
    for (int r = 0; r < 4; ++r) {
      int row = g * 16 + kg * 4 + r;
      out[(size_t)(t0 + row) * 128 + n0 * 16 + rt] = acc[r] + bias + phi[j][r];
    }
  }
}

// ---------------------------------------------------------------------------
extern "C" void kernel_launch(void* const* d_in, const int* in_sizes, int n_in,
                              void* d_out, int out_size, void* d_ws, size_t ws_size,
                              hipStream_t stream) {
  (void)in_sizes; (void)n_in; (void)out_size;
  const float* x     = (const float*)d_in[0];
  const float* gate  = (const float*)d_in[1];
  const float* mask  = (const float*)d_in[2];
  const float* nb6   = (const float*)d_in[3];
  const float* vemb  = (const float*)d_in[4];
  const float* adj   = (const float*)d_in[5];
  const float* spec  = (const float*)d_in[6];
  const float* wspec = (const float*)d_in[7];
  const float* cn_g  = (const float*)d_in[8];
  const float* cn_b  = (const float*)d_in[9];
  const float* Wq    = (const float*)d_in[10];
  const float* Wk    = (const float*)d_in[11];
  const float* Wv    = (const float*)d_in[12];
  const float* bn_g  = (const float*)d_in[13];
  const float* bn_b  = (const float*)d_in[14];
  const float* Wg_w  = (const float*)d_in[15];
  const float* Wg_b  = (const float*)d_in[16];
  const float* g2v   = (const float*)d_in[17];
  const float* v2h   = (const float*)d_in[18];
  const float* pc_w  = (const float*)d_in[19];
  const float* pc_b  = (const float*)d_in[20];
  const float* pn_g  = (const float*)d_in[21];
  const float* pn_b  = (const float*)d_in[22];
  const float* pu_w  = (const float*)d_in[23];
  const float* pu_b  = (const float*)d_in[24];
  const float* pd_w  = (const float*)d_in[25];
  const float* pd_b  = (const float*)d_in[26];

  char* ws = (char*)d_ws;
  bf16_t* Qb   = (bf16_t*)(ws);
  bf16_t* Kb   = (bf16_t*)(ws + (4u << 20));
  bf16_t* Vt   = (bf16_t*)(ws + (8u << 20));
  bf16_t* bnd  = (bf16_t*)(ws + (12u << 20));
  bf16_t* ctr  = (bf16_t*)(ws + (16u << 20));
  float*  vsc  = (float*)(ws + (20u << 20));
  float*  psum = (float*)(ws + (24u << 20));
  bf16_t* wfb  = (bf16_t*)(ws + (24u << 20) + 4096);          // 288 KB
  float*  mlp  = (float*)(ws + (24u << 20) + (512u << 10));   // 512 KB (split2)
  float*  opart= (float*)(ws + (25u << 20));                  // 16 MB (split2)

  // split-S factor for attention: needs 41 MB of ws; fall back to 1 otherwise
  const int nsplit = (ws_size >= ((size_t)41 << 20) + 65536) ? 2 : 1;

  float* f_out = (float*)d_out;                       // field [BT,128]
  float* pi_o  = f_out + (size_t)BT_ * 128;           // pi [BT,64]
  float* al_o  = pi_o + (size_t)BT_ * 64;             // alignment [B,T,T]

  k_prep<<<72, 256, 0, stream>>>(Wq, Wk, Wv, pc_w, pu_w, pd_w, wfb);
  k_qkv<<<512, 256, 0, stream>>>(x, gate, cn_g, cn_b, wfb, Qb, Kb, Vt);
  k_vscores<<<256, 256, 0, stream>>>(x, bn_g, bn_b, Wg_w, Wg_b, nb6, g2v, vemb,
                                     adj, spec, wspec, vsc, psum);
  k_attn<<<256 * nsplit, 256, 0, stream>>>(Qb, Kb, Vt, x, mask, al_o, ctr,
                                           opart, mlp, nsplit);
  if (nsplit == 2)
    k_comb<<<256, 256, 0, stream>>>(x, opart, mlp, ctr);
  k_pi<<<256, 256, 0, stream>>>(x, vsc, psum, vemb, v2h, pi_o, bnd);
  k_ffn<<<512, 256, 0, stream>>>(ctr, bnd, wfb, pc_b, pn_g, pn_b, pu_b, pd_b, f_out);
}

// Round 5
// 351.699 us; speedup vs baseline: 1.0987x; 1.0260x over previous
//
#include <hip/hip_runtime.h>
#include <cmath>

typedef __bf16 bf16_t;
typedef bf16_t bf16x8 __attribute__((ext_vector_type(8)));
typedef bf16_t bf16x4 __attribute__((ext_vector_type(4)));
typedef float f32x4 __attribute__((ext_vector_type(4)));

#define DEVI static __device__ __forceinline__

constexpr int TB = 8;        // batch
constexpr int TT = 2048;     // seq len
constexpr int BT_ = TB * TT; // tokens
constexpr float EPS_LN = 1e-5f;

DEVI f32x4 mfma16(bf16x8 a, bf16x8 b, f32x4 c) {
  return __builtin_amdgcn_mfma_f32_16x16x32_bf16(a, b, c, 0, 0, 0);
}

DEVI bf16x8 cvt8(float4 a, float4 b) {
  bf16x8 v;
  v[0] = (bf16_t)a.x; v[1] = (bf16_t)a.y; v[2] = (bf16_t)a.z; v[3] = (bf16_t)a.w;
  v[4] = (bf16_t)b.x; v[5] = (bf16_t)b.y; v[6] = (bf16_t)b.z; v[7] = (bf16_t)b.w;
  return v;
}

DEVI void gload_lds16(const void* g, void* l) {
  __builtin_amdgcn_global_load_lds(
      (const __attribute__((address_space(1))) unsigned int*)g,
      (__attribute__((address_space(3))) unsigned int*)l, 16, 0, 0);
}

// ---------------------------------------------------------------------------
// K0: pre-pack all MFMA weights f32 -> bf16 in fragment-major layout.
// Order in wf: Wq(16384) Wk(16384) Wv(16384) pc(32768) pu(32768) pd(32768)
// ---------------------------------------------------------------------------
__global__ __launch_bounds__(256) void k_prep(
    const float* __restrict__ Wq, const float* __restrict__ Wk,
    const float* __restrict__ Wv, const float* __restrict__ Wpc,
    const float* __restrict__ Wpu, const float* __restrict__ Wpd,
    bf16_t* __restrict__ wf) {
  int g = blockIdx.x * 256 + threadIdx.x;   // 18432 fragment-groups total
  const float* W;
  bf16_t* dst;
  int rel, lks, Kdim;
  if (g < 6144) {                 // Wq/Wk/Wv: 128x128, KS=4
    int m = g >> 11; rel = g & 2047;
    W = (m == 0) ? Wq : ((m == 1) ? Wk : Wv);
    dst = wf + m * 16384; lks = 2; Kdim = 128;
  } else if (g < 10240) {         // pc_w: 128x256, KS=8
    rel = g - 6144; W = Wpc; dst = wf + 49152; lks = 3; Kdim = 256;
  } else if (g < 14336) {         // pu_w: 256x128, KS=4
    rel = g - 10240; W = Wpu; dst = wf + 81920; lks = 2; Kdim = 128;
  } else {                        // pd_w: 128x256, KS=8
    rel = g - 14336; W = Wpd; dst = wf + 114688; lks = 3; Kdim = 256;
  }
  int lane = rel & 63;
  int fk = (rel >> 6) & ((1 << lks) - 1);
  int n0 = rel >> (6 + lks);
  int row = n0 * 16 + (lane & 15);
  int col = fk * 32 + (lane >> 4) * 8;
  const float* s = W + row * Kdim + col;
  float4 a = *(const float4*)s;
  float4 b = *(const float4*)(s + 4);
  *(bf16x8*)(dst + (size_t)rel * 8) = cvt8(a, b);
}

// ---------------------------------------------------------------------------
// K1: LN(cn) + Q/K/V projections (gate on Q,K). 64 tokens, 4 waves.
// grid 512: sel=blockIdx>>8 splits outputs (sel0: Q + V[0..3]; sel1: K + V[4..7])
// ---------------------------------------------------------------------------
__global__ __launch_bounds__(256) void k_qkv(
    const float* __restrict__ x, const float* __restrict__ gate,
    const float* __restrict__ cn_g, const float* __restrict__ cn_b,
    const bf16_t* __restrict__ wf,
    bf16_t* __restrict__ Qo, bf16_t* __restrict__ Ko, bf16_t* __restrict__ Vt) {
  __shared__ __align__(16) bf16_t sH[64 * 128];   // swizzled 16B blocks
  const int tid = threadIdx.x;
  const int sel = blockIdx.x >> 8;
  const int t0 = (blockIdx.x & 255) * 64;

  { // LayerNorm: 4 threads per token, 32 elems each
    const int tok = tid >> 2, part = tid & 3;
    const float* xr = x + (size_t)(t0 + tok) * 128 + part * 32;
    float v[32];
    float s0 = 0.f, s1 = 0.f;
#pragma unroll
    for (int i = 0; i < 8; ++i) {
      float4 f = ((const float4*)xr)[i];
      v[i * 4 + 0] = f.x; v[i * 4 + 1] = f.y; v[i * 4 + 2] = f.z; v[i * 4 + 3] = f.w;
      s0 += f.x + f.y + f.z + f.w;
      s1 += f.x * f.x + f.y * f.y + f.z * f.z + f.w * f.w;
    }
    s0 += __shfl_xor(s0, 1); s0 += __shfl_xor(s0, 2);
    s1 += __shfl_xor(s1, 1); s1 += __shfl_xor(s1, 2);
    float mean = s0 * (1.f / 128.f);
    float var = s1 * (1.f / 128.f) - mean * mean;
    float rstd = rsqrtf(var + EPS_LN);
#pragma unroll
    for (int j8 = 0; j8 < 4; ++j8) {
      bf16x8 hv;
#pragma unroll
      for (int k = 0; k < 8; ++k) {
        int d = part * 32 + j8 * 8 + k;
        float hn = (v[j8 * 8 + k] - mean) * rstd;
        hv[k] = (bf16_t)(hn * cn_g[d] + cn_b[d]);
      }
      int bl = part * 4 + j8;
      *(bf16x8*)(&sH[tok * 128 + ((bl ^ (tok & 7)) * 8)]) = hv;
    }
  }
  __syncthreads();

  const int wave = tid >> 6, lane = tid & 63;
  const int rt = lane & 15, kg = lane >> 4;
  const int arow = wave * 16 + rt;
  bf16x8 af[4];
#pragma unroll
  for (int ks = 0; ks < 4; ++ks)
    af[ks] = *(const bf16x8*)(&sH[arow * 128 + (((ks * 4 + kg) ^ (rt & 7)) * 8)]);

  const int trow0 = t0 + wave * 16 + kg * 4;  // first of 4 output token rows
  float4 g4 = *(const float4*)(gate + trow0);
  float gr[4] = {g4.x, g4.y, g4.z, g4.w};
  const int b_ = trow0 >> 11;
  const int tloc = trow0 & 2047;

  // Q (sel=0) or K (sel=1), gated
  {
    const bf16_t* wm = wf + sel * 16384;
    bf16_t* O = sel ? Ko : Qo;
#pragma unroll
    for (int n0 = 0; n0 < 8; ++n0) {
      f32x4 acc = {0.f, 0.f, 0.f, 0.f};
#pragma unroll
      for (int ks = 0; ks < 4; ++ks) {
        bf16x8 bf = *(const bf16x8*)(wm + ((size_t)(n0 * 4 + ks) * 64 + lane) * 8);
        acc = mfma16(af[ks], bf, acc);
      }
#pragma unroll
      for (int r = 0; r < 4; ++r)
        O[(size_t)(trow0 + r) * 128 + n0 * 16 + rt] = (bf16_t)(acc[r] * gr[r]);
    }
  }
  // V half (transposed store)
  {
    const bf16_t* wv = wf + 2 * 16384;
#pragma unroll
    for (int n0h = 0; n0h < 4; ++n0h) {
      int n0 = sel * 4 + n0h;
      f32x4 acc = {0.f, 0.f, 0.f, 0.f};
#pragma unroll
      for (int ks = 0; ks < 4; ++ks) {
        bf16x8 bf = *(const bf16x8*)(wv + ((size_t)(n0 * 4 + ks) * 64 + lane) * 8);
        acc = mfma16(af[ks], bf, acc);
      }
      bf16x4 pk;
      pk[0] = (bf16_t)acc[0]; pk[1] = (bf16_t)acc[1];
      pk[2] = (bf16_t)acc[2]; pk[3] = (bf16_t)acc[3];
      *(bf16x4*)(Vt + ((size_t)(b_ * 128 + n0 * 16 + rt)) * 2048 + tloc) = pk;
    }
  }
}

// ---------------------------------------------------------------------------
// K2: boundary v_scores (all fp32 vector math) + per-block |.| partial sums.
// ---------------------------------------------------------------------------
__global__ __launch_bounds__(256) void k_vscores(
    const float* __restrict__ x, const float* __restrict__ bn_g,
    const float* __restrict__ bn_b, const float* __restrict__ Wg_w,
    const float* __restrict__ Wg_b, const float* __restrict__ nb6,
    const float* __restrict__ g2v, const float* __restrict__ vemb,
    const float* __restrict__ adj, const float* __restrict__ spec,
    const float* __restrict__ wspec,
    float* __restrict__ vs_out, float* __restrict__ psum) {
  __shared__ float sWg[768];
  __shared__ float sG2V[192];
  __shared__ float sVE[64 * 33];
  __shared__ float sSP[64 * 33];
  __shared__ float sADJ[64 * 64];
  __shared__ float sRaw[64 * 68];
  __shared__ float sBN[256];
  __shared__ float bsum;
  const int tid = threadIdx.x;
  const int t0 = blockIdx.x * 64;
  if (tid == 0) bsum = 0.f;
  for (int i = tid; i < 768; i += 256) sWg[i] = Wg_w[i];
  for (int i = tid; i < 192; i += 256) sG2V[i] = g2v[i];
  for (int i = tid; i < 256; i += 256) sBN[i] = (i < 128) ? bn_g[i] : bn_b[i - 128];
  for (int i = tid; i < 2048; i += 256) sVE[(i >> 5) * 33 + (i & 31)] = vemb[i];
  for (int i = tid; i < 4096; i += 256) sADJ[i] = adj[i];
  for (int i = tid; i < 2048; i += 256) {
    int s = i >> 5, vv = i & 31;
    float acc = 0.f;
#pragma unroll
    for (int e = 0; e < 16; ++e) acc += spec[s * 16 + e] * wspec[vv * 16 + e];
    sSP[s * 33 + vv] = acc;
  }
  __syncthreads();

  const int tok = tid >> 2, part = tid & 3;
  const float* xr = x + (size_t)(t0 + tok) * 128 + part * 32;
  float v[32];
  float s0 = 0.f, s1 = 0.f;
#pragma unroll
  for (int i = 0; i < 8; ++i) {
    float4 f = ((const float4*)xr)[i];
    v[i * 4 + 0] = f.x; v[i * 4 + 1] = f.y; v[i * 4 + 2] = f.z; v[i * 4 + 3] = f.w;
    s0 += f.x + f.y + f.z + f.w;
    s1 += f.x * f.x + f.y * f.y + f.z * f.z + f.w * f.w;
  }
  s0 += __shfl_xor(s0, 1); s0 += __shfl_xor(s0, 2);
  s1 += __shfl_xor(s1, 1); s1 += __shfl_xor(s1, 2);
  float mean = s0 * (1.f / 128.f);
  float rstd = rsqrtf(s1 * (1.f / 128.f) - mean * mean + EPS_LN);
  float hb[32];
#pragma unroll
  for (int k = 0; k < 32; ++k) {
    int d = part * 32 + k;
    hb[k] = (v[k] - mean) * rstd * sBN[d] + sBN[128 + d];
  }
  float g6[6];
#pragma unroll
  for (int j = 0; j < 6; ++j) {
    float a = 0.f;
#pragma unroll
    for (int k = 0; k < 32; ++k) a += hb[k] * sWg[j * 128 + part * 32 + k];
    a += __shfl_xor(a, 1); a += __shfl_xor(a, 2);
    a += Wg_b[j] + nb6[j];
    g6[j] = 1.f / (1.f + __expf(-a));
  }
  float gp[32];
#pragma unroll
  for (int vv = 0; vv < 32; ++vv) {
    float a = 0.f;
#pragma unroll
    for (int j = 0; j < 6; ++j) a += g6[j] * sG2V[vv * 6 + j];
    gp[vv] = a;
  }
#pragma unroll
  for (int j = 0; j < 16; ++j) {
    int s = part * 16 + j;
    float a = 0.f;
#pragma unroll
    for (int vv = 0; vv < 32; ++vv)
      a += gp[vv] * (sVE[s * 33 + vv] + 0.1f * sSP[s * 33 + vv]);
    sRaw[tok * 68 + s] = a;
  }
  __syncthreads();

  float fin[16];
#pragma unroll
  for (int j = 0; j < 16; ++j) fin[j] = 0.f;
  for (int s = 0; s < 64; ++s) {
    float rv = sRaw[tok * 68 + s];
#pragma unroll
    for (int j = 0; j < 16; ++j) fin[j] += rv * sADJ[s * 64 + part * 16 + j];
  }
  float sa = 0.f;
#pragma unroll
  for (int j = 0; j < 16; ++j) {
    fin[j] = sRaw[tok * 68 + part * 16 + j] + 0.1f * fin[j];
    sa += fabsf(fin[j]);
  }
  float* o = vs_out + (size_t)(t0 + tok) * 64 + part * 16;
#pragma unroll
  for (int j4 = 0; j4 < 4; ++j4) {
    float4 f;
    f.x = fin[j4 * 4 + 0]; f.y = fin[j4 * 4 + 1];
    f.z = fin[j4 * 4 + 2]; f.w = fin[j4 * 4 + 3];
    ((float4*)o)[j4] = f;
  }
#pragma unroll
  for (int m = 1; m <= 32; m <<= 1) sa += __shfl_xor(sa, m);
  if ((tid & 63) == 0) atomicAdd(&bsum, sa);
  __syncthreads();
  if (tid == 0) psum[blockIdx.x] = bsum;
}

// ---------------------------------------------------------------------------
// K3: flash attention + alignment output. Split-S across nsplit blocks.
// KEY (r4): mask loads for the CURRENT tile are issued BEFORE stage(next)'s
// global_load_lds. vmcnt is a single in-order counter, so this keeps the
// softmax's mask-wait from draining the prefetch (which was serializing a
// full HBM round-trip into every tile).
// ---------------------------------------------------------------------------
__global__ __launch_bounds__(256) void k_attn(
    const bf16_t* __restrict__ Q, const bf16_t* __restrict__ Kp,
    const bf16_t* __restrict__ Vt, const float* __restrict__ x,
    const float* __restrict__ mask, float* __restrict__ align_out,
    bf16_t* __restrict__ center, float* __restrict__ o_part,
    float* __restrict__ ml_part, int nsplit) {
  __shared__ __align__(16) bf16_t sK[2][64 * 128];
  __shared__ __align__(16) bf16_t sV[2][128 * 64];
  __shared__ __align__(16) bf16_t sP[4][16 * 72];   // +8 pad per row
  const int tid = threadIdx.x;
  const int b_ = blockIdx.x & 7;          // XCD-affine batch
  const int qt = (blockIdx.x >> 3) & 31;
  const int sq = blockIdx.x >> 8;
  const int ntile = 32 / nsplit;
  const int st0 = sq * ntile;
  const int wave = tid >> 6, lane = tid & 63;
  const int rt = lane & 15, kg = lane >> 4;
  const size_t tq0 = (size_t)b_ * TT + qt * 64;

  bf16x8 qf[4];
#pragma unroll
  for (int ks = 0; ks < 4; ++ks)
    qf[ks] = *(const bf16x8*)(Q + (tq0 + wave * 16 + rt) * 128 + ks * 32 + kg * 8);

  f32x4 o[8];
  f32x4 zero4 = {0.f, 0.f, 0.f, 0.f};
#pragma unroll
  for (int i = 0; i < 8; ++i) o[i] = zero4;
  float m[4], l[4];
#pragma unroll
  for (int r = 0; r < 4; ++r) { m[r] = -INFINITY; l[r] = 0.f; }
  const float inv_sc = 0.08838834764831845f;  // 1/sqrt(128)
  const int tqr = qt * 64 + wave * 16 + kg * 4;
  const int koff = wave * 1024 + lane * 16;

  auto stage = [&](int buf, int st) {
    const int sb2 = st * 64;
#pragma unroll
    for (int i = 0; i < 4; ++i) {
      int off = i * 4096 + koff;
      int row = off >> 8;
      int c16 = (off >> 4) & 15;
      const char* src = (const char*)Kp +
          ((size_t)(b_ * TT + sb2 + row) * 128 + ((c16 ^ (row & 7)) * 8)) * 2;
      gload_lds16(src, (char*)(&sK[buf][0]) + i * 4096 + wave * 1024);
    }
#pragma unroll
    for (int i = 0; i < 4; ++i) {
      int off = i * 4096 + koff;
      int row = off >> 7;
      int c16 = (off >> 4) & 7;
      const char* src = (const char*)Vt +
          ((size_t)(b_ * 128 + row) * 2048 + sb2 + ((c16 ^ (row & 7)) * 8)) * 2;
      gload_lds16(src, (char*)(&sV[buf][0]) + i * 4096 + wave * 1024);
    }
  };

  int cur = 0;
  stage(0, st0);
  for (int it = 0; it < ntile; ++it) {
    const int sb = (st0 + it) * 64;
    __syncthreads();   // drains stage(cur) (vmcnt 0) + prior-iter LDS reads done

    // mask preload for THIS tile -- must issue before stage(next) so the
    // softmax's wait leaves the 16 prefetch loads in flight (counted vmcnt).
    float mreg[4][4];
#pragma unroll
    for (int ct = 0; ct < 4; ++ct) {
      const int scol = sb + ct * 16 + rt;
#pragma unroll
      for (int r = 0; r < 4; ++r)
        mreg[ct][r] = mask[(size_t)(tqr + r) * TT + scol];
    }
    __builtin_amdgcn_sched_barrier(0);   // pin: mask loads issue before stage

    if (it + 1 < ntile) stage(cur ^ 1, st0 + it + 1);  // prefetch overlaps compute

    // scores S = Q K^T / sqrt(D) + mask ; write alignment; online softmax
    float p[4][4];
#pragma unroll
    for (int ct = 0; ct < 4; ++ct) {
      const int brow = ct * 16 + rt;
      f32x4 acc = zero4;
#pragma unroll
      for (int ks = 0; ks < 4; ++ks) {
        bf16x8 kf = *(const bf16x8*)(&sK[cur][brow * 128 + (((ks * 4 + kg) ^ (rt & 7)) * 8)]);
        acc = mfma16(qf[ks], kf, acc);
      }
      const int scol = sb + ct * 16 + rt;
#pragma unroll
      for (int r = 0; r < 4; ++r) {
        float sv = acc[r] * inv_sc + mreg[ct][r];
        align_out[((size_t)b_ * TT + tqr + r) * TT + scol] = sv;
        p[ct][r] = sv;
      }
    }
    float mn[4], fsc[4];
#pragma unroll
    for (int r = 0; r < 4; ++r) {
      float pm = fmaxf(fmaxf(p[0][r], p[1][r]), fmaxf(p[2][r], p[3][r]));
#pragma unroll
      for (int dm = 1; dm <= 8; dm <<= 1) pm = fmaxf(pm, __shfl_xor(pm, dm));
      mn[r] = fmaxf(m[r], pm);
      fsc[r] = __expf(m[r] - mn[r]);
      m[r] = mn[r];
    }
    float rs[4] = {0.f, 0.f, 0.f, 0.f};
#pragma unroll
    for (int ct = 0; ct < 4; ++ct)
#pragma unroll
      for (int r = 0; r < 4; ++r) {
        float pe = __expf(p[ct][r] - mn[r]);
        p[ct][r] = pe;
        rs[r] += pe;
      }
#pragma unroll
    for (int r = 0; r < 4; ++r) {
#pragma unroll
      for (int dm = 1; dm <= 8; dm <<= 1) rs[r] += __shfl_xor(rs[r], dm);
      l[r] = l[r] * fsc[r] + rs[r];
    }
#pragma unroll
    for (int i = 0; i < 8; ++i) {
      o[i][0] *= fsc[0]; o[i][1] *= fsc[1]; o[i][2] *= fsc[2]; o[i][3] *= fsc[3];
    }
    // P -> bf16 -> per-wave LDS (same-wave write->read, in-order DS)
#pragma unroll
    for (int ct = 0; ct < 4; ++ct)
#pragma unroll
      for (int r = 0; r < 4; ++r)
        sP[wave][(kg * 4 + r) * 72 + ct * 16 + rt] = (bf16_t)p[ct][r];
    asm volatile("" ::: "memory");
    bf16x8 pf[2];
#pragma unroll
    for (int ks = 0; ks < 2; ++ks)
      pf[ks] = *(const bf16x8*)(&sP[wave][rt * 72 + ks * 32 + kg * 8]);
#pragma unroll
    for (int n0 = 0; n0 < 8; ++n0) {
      const int brow = n0 * 16 + rt;
      f32x4 acc = o[n0];
#pragma unroll
      for (int ks = 0; ks < 2; ++ks) {
        bf16x8 vf = *(const bf16x8*)(&sV[cur][brow * 64 + (((ks * 4 + kg) ^ (rt & 7)) * 8)]);
        acc = mfma16(pf[ks], vf, acc);
      }
      o[n0] = acc;
    }
    cur ^= 1;
  }

  const size_t trow = tq0 + wave * 16 + kg * 4;
  if (nsplit == 1) {
    float il[4];
#pragma unroll
    for (int r = 0; r < 4; ++r) il[r] = 1.f / l[r];
#pragma unroll
    for (int n0 = 0; n0 < 8; ++n0) {
      int col = n0 * 16 + rt;
#pragma unroll
      for (int r = 0; r < 4; ++r) {
        float val = o[n0][r] * il[r] + x[(trow + r) * 128 + col];
        center[(trow + r) * 128 + col] = (bf16_t)val;
      }
    }
  } else {
#pragma unroll
    for (int n0 = 0; n0 < 8; ++n0) {
      int col = n0 * 16 + rt;
#pragma unroll
      for (int r = 0; r < 4; ++r)
        o_part[((size_t)sq * BT_ + trow + r) * 128 + col] = o[n0][r];
    }
    if (rt == 0) {
#pragma unroll
      for (int r = 0; r < 4; ++r) {
        size_t t = (size_t)sq * BT_ + trow + r;
        ml_part[t * 2] = m[r];
        ml_part[t * 2 + 1] = l[r];
      }
    }
  }
}

// ---------------------------------------------------------------------------
// K3b: merge split-S partials -> center = x + (sum_i o_i*w_i)/(sum_i l_i*w_i)
// ---------------------------------------------------------------------------
__global__ __launch_bounds__(256) void k_comb(
    const float* __restrict__ x, const float* __restrict__ o_part,
    const float* __restrict__ ml_part, bf16_t* __restrict__ center) {
  const int tid = threadIdx.x;
  const int tok = blockIdx.x * 64 + (tid >> 2);
  const int part = tid & 3;
  float m0 = ml_part[(size_t)tok * 2];
  float l0 = ml_part[(size_t)tok * 2 + 1];
  float m1 = ml_part[((size_t)BT_ + tok) * 2];
  float l1 = ml_part[((size_t)BT_ + tok) * 2 + 1];
  float M = fmaxf(m0, m1);
  float w0 = __expf(m0 - M), w1 = __expf(m1 - M);
  float inv = 1.f / (l0 * w0 + l1 * w1);
  w0 *= inv; w1 *= inv;
  const float* xr = x + (size_t)tok * 128 + part * 32;
  const float* o0 = o_part + (size_t)tok * 128 + part * 32;
  const float* o1 = o_part + ((size_t)BT_ + tok) * 128 + part * 32;
  bf16_t* cr = center + (size_t)tok * 128 + part * 32;
#pragma unroll
  for (int c = 0; c < 4; ++c) {
    float4 a0 = ((const float4*)(o0 + c * 8))[0];
    float4 b0 = ((const float4*)(o0 + c * 8))[1];
    float4 a1 = ((const float4*)(o1 + c * 8))[0];
    float4 b1 = ((const float4*)(o1 + c * 8))[1];
    float4 xa = ((const float4*)(xr + c * 8))[0];
    float4 xb = ((const float4*)(xr + c * 8))[1];
    bf16x8 ov;
    ov[0] = (bf16_t)(a0.x * w0 + a1.x * w1 + xa.x);
    ov[1] = (bf16_t)(a0.y * w0 + a1.y * w1 + xa.y);
    ov[2] = (bf16_t)(a0.z * w0 + a1.z * w1 + xa.z);
    ov[3] = (bf16_t)(a0.w * w0 + a1.w * w1 + xa.w);
    ov[4] = (bf16_t)(b0.x * w0 + b1.x * w1 + xb.x);
    ov[5] = (bf16_t)(b0.y * w0 + b1.y * w1 + xb.y);
    ov[6] = (bf16_t)(b0.z * w0 + b1.z * w1 + xb.z);
    ov[7] = (bf16_t)(b0.w * w0 + b1.w * w1 + xb.w);
    *(bf16x8*)(cr + c * 8) = ov;
  }
}

// ---------------------------------------------------------------------------
// K4: mean_abs finalize, softmax over NV=64, top-8 hard routing, pi output,
// vertex_ctx -> boundary signal (all fp32). 64 tokens/block, 4 lanes/token.
// ---------------------------------------------------------------------------
__global__ __launch_bounds__(256) void k_pi(
    const float* __restrict__ x, const float* __restrict__ vs,
    const float* __restrict__ psum, const float* __restrict__ vemb,
    const float* __restrict__ v2h,
    float* __restrict__ pi_out, bf16_t* __restrict__ bound) {
  __shared__ float red[256];
  __shared__ float sVE[64 * 33];
  __shared__ float sV2H[128 * 33];
  const int tid = threadIdx.x;
  const int t0 = blockIdx.x * 64;
  red[tid] = psum[tid];
  for (int i = tid; i < 2048; i += 256) sVE[(i >> 5) * 33 + (i & 31)] = vemb[i];
  for (int i = tid; i < 4096; i += 256) sV2H[(i >> 5) * 33 + (i & 31)] = v2h[i];
  __syncthreads();
#pragma unroll
  for (int s = 128; s > 0; s >>= 1) {
    if (tid < s) red[tid] += red[tid + s];
    __syncthreads();
  }
  float mean_abs = fmaxf(red[0] * (1.f / 1048576.f), 1e-6f);
  float s3 = 3.f / mean_abs;

  const int tok = tid >> 2, part = tid & 3;
  const int tg = t0 + tok;
  const float* vr = vs + (size_t)tg * 64 + part * 16;
  float lg[16];
  float mx = -INFINITY;
#pragma unroll
  for (int j4 = 0; j4 < 4; ++j4) {
    float4 f = ((const float4*)vr)[j4];
    lg[j4 * 4 + 0] = f.x * s3; lg[j4 * 4 + 1] = f.y * s3;
    lg[j4 * 4 + 2] = f.z * s3; lg[j4 * 4 + 3] = f.w * s3;
    mx = fmaxf(mx, fmaxf(fmaxf(lg[j4 * 4 + 0], lg[j4 * 4 + 1]),
                         fmaxf(lg[j4 * 4 + 2], lg[j4 * 4 + 3])));
  }
  mx = fmaxf(mx, __shfl_xor(mx, 1));
  mx = fmaxf(mx, __shfl_xor(mx, 2));
  float e[16];
  float tot = 0.f;
#pragma unroll
  for (int j = 0; j < 16; ++j) { e[j] = __expf(lg[j] - mx); tot += e[j]; }
  tot += __shfl_xor(tot, 1); tot += __shfl_xor(tot, 2);

  unsigned used = 0u;
  float tsum = 0.f;
#pragma unroll
  for (int it = 0; it < 8; ++it) {
    float bv = -INFINITY;
    int bi = 0;
#pragma unroll
    for (int j = 0; j < 16; ++j) {
      bool ok = !(used & (1u << j)) && (e[j] > bv);
      bv = ok ? e[j] : bv;
      bi = ok ? j : bi;
    }
    int gi = part * 16 + bi;
#pragma unroll
    for (int dm = 1; dm <= 2; dm <<= 1) {
      float ov = __shfl_xor(bv, dm);
      int oi = __shfl_xor(gi, dm);
      bool take = (ov > bv) || (ov == bv && oi < gi);
      bv = take ? ov : bv;
      gi = take ? oi : gi;
    }
    tsum += bv;
    if ((gi >> 4) == part) used |= 1u << (gi & 15);
  }
  float inv_tot = 1.f / tot;
  float inv_d = 1.f / (tsum * inv_tot + 1e-8f);
  float pi[16];
#pragma unroll
  for (int j = 0; j < 16; ++j)
    pi[j] = (used & (1u << j)) ? e[j] * inv_tot * inv_d : 0.f;
  float* po = pi_out + (size_t)tg * 64 + part * 16;
#pragma unroll
  for (int j4 = 0; j4 < 4; ++j4) {
    float4 f;
    f.x = pi[j4 * 4 + 0]; f.y = pi[j4 * 4 + 1];
    f.z = pi[j4 * 4 + 2]; f.w = pi[j4 * 4 + 3];
    ((float4*)po)[j4] = f;
  }
  float vc[32];
#pragma unroll
  for (int vv = 0; vv < 32; ++vv) vc[vv] = 0.f;
#pragma unroll
  for (int j = 0; j < 16; ++j) {
    float p = pi[j];
    int s = part * 16 + j;
#pragma unroll
    for (int vv = 0; vv < 32; ++vv) vc[vv] += p * sVE[s * 33 + vv];
  }
#pragma unroll
  for (int vv = 0; vv < 32; ++vv) {
    vc[vv] += __shfl_xor(vc[vv], 1);
    vc[vv] += __shfl_xor(vc[vv], 2);
  }
  const float* xr = x + (size_t)tg * 128 + part * 32;
  bf16_t* br = bound + (size_t)tg * 128 + part * 32;
#pragma unroll
  for (int d8 = 0; d8 < 4; ++d8) {
    float4 xa = ((const float4*)xr)[d8 * 2];
    float4 xb = ((const float4*)xr)[d8 * 2 + 1];
    float xv[8] = {xa.x, xa.y, xa.z, xa.w, xb.x, xb.y, xb.z, xb.w};
    bf16x8 ov;
#pragma unroll
    for (int k = 0; k < 8; ++k) {
      int d = part * 32 + d8 * 8 + k;
      float a = 0.f;
#pragma unroll
      for (int vv = 0; vv < 32; ++vv) a += vc[vv] * sV2H[d * 33 + vv];
      ov[k] = (bf16_t)(xv[k] + a);
    }
    *(bf16x8*)(br + d8 * 8) = ov;
  }
}

// ---------------------------------------------------------------------------
// K5: field FFN. 32 tokens/block, grid 512 (2 blocks/CU -> 8 waves/CU).
// 4 waves: g=wave&1 -> row group (16 rows), h=wave>>1 -> n0 half.
// ---------------------------------------------------------------------------
__global__ __launch_bounds__(256) void k_ffn(
    const bf16_t* __restrict__ center, const bf16_t* __restrict__ bound,
    const bf16_t* __restrict__ wf,
    const float* __restrict__ pc_b, const float* __restrict__ pn_g,
    const float* __restrict__ pn_b, const float* __restrict__ pu_b,
    const float* __restrict__ pd_b, float* __restrict__ out) {
  __shared__ __align__(16) bf16_t sH[32 * 128];   // phi_h (swizzled bytes)
  __shared__ __align__(16) bf16_t sG[32 * 256];   // gelu acts (swizzled bytes)
  __shared__ float sLN[2][32][2];                 // [h][row][{s0,s1}]
  const bf16_t* wpc = wf + 49152;
  const bf16_t* wpu = wf + 81920;
  const bf16_t* wpd = wf + 114688;
  const int tid = threadIdx.x;
  const int t0 = blockIdx.x * 32;
  const int wave = tid >> 6, lane = tid & 63;
  const int g = wave & 1, h = wave >> 1;
  const int rt = lane & 15, kg = lane >> 4;
  const int arow = g * 16 + rt;

  // phase A: phi = concat @ pc_w^T + pc_b ; wave covers n0 in [4h, 4h+4)
  bf16x8 af[8];
#pragma unroll
  for (int ks = 0; ks < 8; ++ks) {
    const bf16_t* src = (ks < 4)
        ? (center + (size_t)(t0 + arow) * 128 + ks * 32 + kg * 8)
        : (bound + (size_t)(t0 + arow) * 128 + (ks - 4) * 32 + kg * 8);
    af[ks] = *(const bf16x8*)src;
  }
  f32x4 phi[4];
#pragma unroll
  for (int j = 0; j < 4; ++j) {
    int n0 = 4 * h + j;
    f32x4 acc = {0.f, 0.f, 0.f, 0.f};
#pragma unroll
    for (int ks = 0; ks < 8; ++ks) {
      bf16x8 bf = *(const bf16x8*)(wpc + ((size_t)(n0 * 8 + ks) * 64 + lane) * 8);
      acc = mfma16(af[ks], bf, acc);
    }
    float bias = pc_b[n0 * 16 + rt];
    acc[0] += bias; acc[1] += bias; acc[2] += bias; acc[3] += bias;
    phi[j] = acc;
  }
  // LN partials over this wave's 64 cols, rows g*16+kg*4+r
#pragma unroll
  for (int r = 0; r < 4; ++r) {
    float s0 = 0.f, s1 = 0.f;
#pragma unroll
    for (int j = 0; j < 4; ++j) {
      float vv = phi[j][r];
      s0 += vv; s1 += vv * vv;
    }
#pragma unroll
    for (int dm = 1; dm <= 8; dm <<= 1) {
      s0 += __shfl_xor(s0, dm);
      s1 += __shfl_xor(s1, dm);
    }
    if (rt == 0) {
      int row = g * 16 + kg * 4 + r;
      sLN[h][row][0] = s0;
      sLN[h][row][1] = s1;
    }
  }
  __syncthreads();
  float mean[4], rstd[4];
#pragma unroll
  for (int r = 0; r < 4; ++r) {
    int row = g * 16 + kg * 4 + r;
    float s0 = sLN[0][row][0] + sLN[1][row][0];
    float s1 = sLN[0][row][1] + sLN[1][row][1];
    mean[r] = s0 * (1.f / 128.f);
    float var = s1 * (1.f / 128.f) - mean[r] * mean[r];
    rstd[r] = rsqrtf(var + EPS_LN);
  }
#pragma unroll
  for (int j = 0; j < 4; ++j) {
    int col = (4 * h + j) * 16 + rt;
    float gg = pn_g[col], bb = pn_b[col];
#pragma unroll
    for (int r = 0; r < 4; ++r) {
      float hv = (phi[j][r] - mean[r]) * rstd[r] * gg + bb;
      int row = g * 16 + kg * 4 + r;
      *(bf16_t*)((char*)sH + row * 256 + ((2 * col) ^ ((row & 7) << 4))) = (bf16_t)hv;
    }
  }
  __syncthreads();

  // phase B: u = phi_h @ pu_w^T + pu_b ; gelu exact -> sG. wave: n0 in [8h, 8h+8)
  bf16x8 ah[4];
#pragma unroll
  for (int ks = 0; ks < 4; ++ks)
    ah[ks] = *(const bf16x8*)((const char*)sH + arow * 256 +
                              (((ks * 4 + kg) ^ (rt & 7)) * 16));
#pragma unroll
  for (int j2 = 0; j2 < 8; ++j2) {
    int n0 = 8 * h + j2;
    f32x4 acc = {0.f, 0.f, 0.f, 0.f};
#pragma unroll
    for (int ks = 0; ks < 4; ++ks) {
      bf16x8 bf = *(const bf16x8*)(wpu + ((size_t)(n0 * 4 + ks) * 64 + lane) * 8);
      acc = mfma16(ah[ks], bf, acc);
    }
    int col = n0 * 16 + rt;
    float bias = pu_b[col];
#pragma unroll
    for (int r = 0; r < 4; ++r) {
      float uv = acc[r] + bias;
      float gv = 0.5f * uv * (1.f + erff(uv * 0.7071067811865476f));
      int row = g * 16 + kg * 4 + r;
      *(bf16_t*)((char*)sG + row * 512 + ((2 * col) ^ ((row & 7) << 4))) = (bf16_t)gv;
    }
  }
  __syncthreads();

  // phase C: out = gelu @ pd_w^T + pd_b + phi. wave: n0 in [4h, 4h+4)
  bf16x8 ag[8];
#pragma unroll
  for (int ks = 0; ks < 8; ++ks)
    ag[ks] = *(const bf16x8*)((const char*)sG + arow * 512 +
                              (((ks * 4 + kg) ^ (rt & 7)) * 16));
#pragma unroll
  for (int j = 0; j < 4; ++j) {
    int n0 = 4 * h + j;
    f32x4 acc = {0.f, 0.f, 0.f, 0.f};
#pragma unroll
    for (int ks = 0; ks < 8; ++ks) {
      bf16x8 bf = *(const bf16x8*)(wpd + ((size_t)(n0 * 8 + ks) * 64 + lane) * 8);
      acc = mfma16(ag[ks], bf, acc);
    }
    float bias = pd_b[n0 * 16 + rt];
#pragma unroll
    for (int r = 0; r < 4; ++r) {
      int row = g * 16 + kg * 4 + r;
      out[(size_t)(t0 + row) * 128 + n0 * 16 + rt] = acc[r] + bias + phi[j][r];
    }
  }
}

// ---------------------------------------------------------------------------
extern "C" void kernel_launch(void* const* d_in, const int* in_sizes, int n_in,
                              void* d_out, int out_size, void* d_ws, size_t ws_size,
                              hipStream_t stream) {
  (void)in_sizes; (void)n_in; (void)out_size;
  const float* x     = (const float*)d_in[0];
  const float* gate  = (const float*)d_in[1];
  const float* mask  = (const float*)d_in[2];
  const float* nb6   = (const float*)d_in[3];
  const float* vemb  = (const float*)d_in[4];
  const float* adj   = (const float*)d_in[5];
  const float* spec  = (const float*)d_in[6];
  const float* wspec = (const float*)d_in[7];
  const float* cn_g  = (const float*)d_in[8];
  const float* cn_b  = (const float*)d_in[9];
  const float* Wq    = (const float*)d_in[10];
  const float* Wk    = (const float*)d_in[11];
  const float* Wv    = (const float*)d_in[12];
  const float* bn_g  = (const float*)d_in[13];
  const float* bn_b  = (const float*)d_in[14];
  const float* Wg_w  = (const float*)d_in[15];
  const float* Wg_b  = (const float*)d_in[16];
  const float* g2v   = (const float*)d_in[17];
  const float* v2h   = (const float*)d_in[18];
  const float* pc_w  = (const float*)d_in[19];
  const float* pc_b  = (const float*)d_in[20];
  const float* pn_g  = (const float*)d_in[21];
  const float* pn_b  = (const float*)d_in[22];
  const float* pu_w  = (const float*)d_in[23];
  const float* pu_b  = (const float*)d_in[24];
  const float* pd_w  = (const float*)d_in[25];
  const float* pd_b  = (const float*)d_in[26];

  char* ws = (char*)d_ws;
  bf16_t* Qb   = (bf16_t*)(ws);
  bf16_t* Kb   = (bf16_t*)(ws + (4u << 20));
  bf16_t* Vt   = (bf16_t*)(ws + (8u << 20));
  bf16_t* bnd  = (bf16_t*)(ws + (12u << 20));
  bf16_t* ctr  = (bf16_t*)(ws + (16u << 20));
  float*  vsc  = (float*)(ws + (20u << 20));
  float*  psum = (float*)(ws + (24u << 20));
  bf16_t* wfb  = (bf16_t*)(ws + (24u << 20) + 4096);          // 288 KB
  float*  mlp  = (float*)(ws + (24u << 20) + (512u << 10));   // 512 KB (split2)
  float*  opart= (float*)(ws + (25u << 20));                  // 16 MB (split2)

  // split-S factor for attention: needs 41 MB of ws; fall back to 1 otherwise
  const int nsplit = (ws_size >= ((size_t)41 << 20) + 65536) ? 2 : 1;

  float* f_out = (float*)d_out;                       // field [BT,128]
  float* pi_o  = f_out + (size_t)BT_ * 128;           // pi [BT,64]
  float* al_o  = pi_o + (size_t)BT_ * 64;             // alignment [B,T,T]

  k_prep<<<72, 256, 0, stream>>>(Wq, Wk, Wv, pc_w, pu_w, pd_w, wfb);
  k_qkv<<<512, 256, 0, stream>>>(x, gate, cn_g, cn_b, wfb, Qb, Kb, Vt);
  k_vscores<<<256, 256, 0, stream>>>(x, bn_g, bn_b, Wg_w, Wg_b, nb6, g2v, vemb,
                                     adj, spec, wspec, vsc, psum);
  k_attn<<<256 * nsplit, 256, 0, stream>>>(Qb, Kb, Vt, x, mask, al_o, ctr,
                                           opart, mlp, nsplit);
  if (nsplit == 2)
    k_comb<<<256, 256, 0, stream>>>(x, opart, mlp, ctr);
  k_pi<<<256, 256, 0, stream>>>(x, vsc, psum, vemb, v2h, pi_o, bnd);
  k_ffn<<<512, 256, 0, stream>>>(ctr, bnd, wfb, pc_b, pn_g, pn_b, pu_b, pd_b, f_out);
}